// Round 10
// baseline (560.265 us; speedup 1.0000x reference)
//
#include <hip/hip_runtime.h>
#include <stdint.h>

typedef unsigned short u16;
typedef __attribute__((ext_vector_type(8))) __bf16 bf16x8;
typedef __attribute__((ext_vector_type(4))) float f32x4;

#define B_TOTAL 65536
#define KPAD1   1472   // 1424 padded to multiple of 64 (23 K-steps)

__device__ __forceinline__ u16 f2bf(float f) {
  union { float f; uint32_t u; } v; v.f = f;
  uint32_t r = v.u + 0x7fffu + ((v.u >> 16) & 1u);
  return (u16)(r >> 16);
}
__device__ __forceinline__ float bf2f(u16 h) {
  union { uint32_t u; float f; } v; v.u = ((uint32_t)h) << 16;
  return v.f;
}

__device__ __forceinline__ void gload16(const void* g, void* lds) {
  __builtin_amdgcn_global_load_lds(
      (const __attribute__((address_space(1))) uint32_t*)g,
      (__attribute__((address_space(3))) uint32_t*)lds, 16, 0, 0);
}

// ---------------- weight prep: f32 [K][N] -> bf16 [N][Kpad] (transposed, zero-padded K)
__global__ void wprep_kernel(const float* __restrict__ W, u16* __restrict__ Wt,
                             int K, int N, int Kpad) {
  int o = blockIdx.x * 256 + threadIdx.x;
  if (o >= N * Kpad) return;
  int k = o % Kpad;
  int n = o / Kpad;
  float v = (k < K) ? W[(size_t)k * N + n] : 0.0f;
  Wt[o] = f2bf(v);
}

// ---------------- gather + concat -> X bf16 [Bc][1472]
struct GatherArgs {
  const int*   idx[15];
  const float* E[15];
  const int*   idx_u;
  const float* E_u;
};

constexpr int FDIM[15] = {128,128,128,16,16,96,144,64,80,64,48,144,96,16,144};
constexpr int FOFF[15] = {0,128,256,384,400,416,512,656,720,800,864,912,1056,1152,1168};

__global__ void gather_kernel(GatherArgs p, u16* __restrict__ X, int row_base) {
  const int lane = threadIdx.x & 63;
  const int row  = blockIdx.x * 4 + (threadIdx.x >> 6);
  const int grow = row_base + row;
  u16* xrow = X + (size_t)row * KPAD1;

#pragma unroll
  for (int f = 0; f < 15; ++f) {
    const int id = p.idx[f][grow];
    const float* src = p.E[f] + (size_t)id * FDIM[f];
    const int ng = FDIM[f] / 4;
    if (lane < ng) {
      const float4 v = *reinterpret_cast<const float4*>(src + lane * 4);
      ushort4 o;
      o.x = f2bf(v.x); o.y = f2bf(v.y); o.z = f2bf(v.z); o.w = f2bf(v.w);
      *reinterpret_cast<ushort4*>(xrow + FOFF[f] + lane * 4) = o;
    }
  }
  // userids mean-pool over 50, dim 112: lanes 0..27 take 4 cols each, 2-deep ILP
  const int* iu = p.idx_u + (size_t)grow * 50;
  if (lane < 28) {
    float4 s0 = {0.f, 0.f, 0.f, 0.f}, s1 = {0.f, 0.f, 0.f, 0.f};
#pragma unroll 5
    for (int j = 0; j < 50; j += 2) {
      const int i0 = iu[j];
      const int i1 = iu[j + 1];
      const float4 v0 = *reinterpret_cast<const float4*>(p.E_u + (size_t)i0 * 112 + lane * 4);
      const float4 v1 = *reinterpret_cast<const float4*>(p.E_u + (size_t)i1 * 112 + lane * 4);
      s0.x += v0.x; s0.y += v0.y; s0.z += v0.z; s0.w += v0.w;
      s1.x += v1.x; s1.y += v1.y; s1.z += v1.z; s1.w += v1.w;
    }
    const float inv = 1.0f / 50.0f;
    ushort4 o;
    o.x = f2bf((s0.x + s1.x) * inv);
    o.y = f2bf((s0.y + s1.y) * inv);
    o.z = f2bf((s0.z + s1.z) * inv);
    o.w = f2bf((s0.w + s1.w) * inv);
    *reinterpret_cast<ushort4*>(xrow + 1312 + lane * 4) = o;
  } else if (lane < 40) {
    // zero-pad cols 1424..1471 (12 lanes x 4 cols)
    ushort4 z; z.x = 0; z.y = 0; z.z = 0; z.w = 0;
    *reinterpret_cast<ushort4*>(xrow + 1424 + (lane - 28) * 4) = z;
  }
}

// ---------------- gemm8: 256x256 tile, K-step=64, m201-style 4-phase interleave
// C[M][N] = relu(A[M][K] * Wt[N][K]^T + bias), bf16 out.
// LDS: 2 dbuf x 4 halves (A@k0, B@k0, A@k1, B@k1), each half = swizzled [256x32]
// 16KB block (physical 16B-slot = logical ^ ((row>>1)&3); staged via linear
// global_load_lds from inverse-swizzled source).
// Phase p of step t: {4-8 ds_reads; stage 1 half of step t+1; barrier;
// lgkmcnt(0); sched_barrier; setprio(1); 16 MFMA; setprio(0); barrier}.
// vmcnt(4) at p1/p3 tails only (ledger: 4 outstanding at each phase-pair
// boundary; retires exactly the 2 halves about to be read; 0 on last step).

template<int K>
__global__ __launch_bounds__(512, 2) void gemm8(
    const u16* __restrict__ A, const u16* __restrict__ Wt,
    const float* __restrict__ bias, u16* __restrict__ C,
    int N, int gm) {
  extern __shared__ __align__(16) u16 lds[];
  constexpr int NT = K / 64;     // K-steps
  const int tid  = threadIdx.x;
  const int w    = tid >> 6;
  const int lane = tid & 63;
  const int fr   = lane & 15;
  const int kg   = lane >> 4;
  const int wm   = w >> 2;      // 0..1
  const int wn   = w & 3;       // 0..3

  // bijective XCD swizzle (m204), M-major so an XCD chunk shares the weight panel
  const int nwg = gridDim.x;
  const int q = nwg >> 3, r = nwg & 7;
  const int xcd = blockIdx.x & 7, lid = blockIdx.x >> 3;
  const int swz = (xcd < r) ? (xcd * (q + 1) + lid) : (r * (q + 1) + (xcd - r) * q + lid);
  const int bm = swz % gm, bn = swz / gm;
  const int rowBase = bm * 256, colBase = bn * 256;

  // staging: thread i covers LDS bytes i*16 of an 8192-elem half (2 gloads)
  // logical slot fetched from global = (lane&3) ^ ((lane>>3)&3)
  const int srow  = lane >> 2;
  const int sslot = (lane & 3) ^ ((lane >> 3) & 3);
  const u16* Asrc0 = A  + (size_t)(rowBase + w * 16 + srow) * K + sslot * 8;
  const u16* Bsrc0 = Wt + (size_t)(colBase + w * 16 + srow) * K + sslot * 8;
  const size_t rstep = (size_t)128 * K;

  f32x4 acc[8][4];
#pragma unroll
  for (int m = 0; m < 8; ++m)
#pragma unroll
    for (int n = 0; n < 4; ++n)
      acc[m][n] = f32x4{0.f, 0.f, 0.f, 0.f};

  // read-side swizzled fragment bases within a half: slot = kg ^ ((fr>>1)&3)
  const int aslot8 = (kg ^ ((fr >> 1) & 3)) * 8;
  const int ardA = (wm * 128 + fr) * 32 + aslot8;   // +m*512, +2048 for row-half 1
  const int ardB = (wn * 64 + fr) * 32 + aslot8;    // +n*512

  auto stageHalf = [&](const u16* src0, int ldsElemBase, int kElemOff) {
    const u16* s = src0 + kElemOff;
    gload16(s,         &lds[ldsElemBase + w * 512]);
    gload16(s + rstep, &lds[ldsElemBase + 4096 + w * 512]);
  };

  // prologue: stage step 0's 4 halves (order A_k0, B_k0, A_k1, B_k1)
  stageHalf(Asrc0, 0,     0);
  stageHalf(Bsrc0, 8192,  0);
  stageHalf(Asrc0, 16384, 32);
  stageHalf(Bsrc0, 24576, 32);
  asm volatile("s_waitcnt vmcnt(4)" ::: "memory");   // A_k0,B_k0 ready; k1 in flight
  __builtin_amdgcn_s_barrier();

#pragma unroll 1
  for (int t = 0; t < NT; ++t) {
    const int c  = (t & 1) << 15;          // current dbuf (32768 elems)
    const int o  = ((t + 1) & 1) << 15;    // staging dbuf
    const bool st = (t + 1) < NT;
    const int kN = (t + 1) * 64;

    bf16x8 a0, a1, a2, a3, b0, b1, b2, b3;

    // ---------- p0: A row-half 0 @k0 + all B @k0 (8 reads); stage A_k0(next)
    a0 = *(const bf16x8*)&lds[c + ardA + 0 * 512];
    a1 = *(const bf16x8*)&lds[c + ardA + 1 * 512];
    a2 = *(const bf16x8*)&lds[c + ardA + 2 * 512];
    a3 = *(const bf16x8*)&lds[c + ardA + 3 * 512];
    b0 = *(const bf16x8*)&lds[c + 8192 + ardB + 0 * 512];
    b1 = *(const bf16x8*)&lds[c + 8192 + ardB + 1 * 512];
    b2 = *(const bf16x8*)&lds[c + 8192 + ardB + 2 * 512];
    b3 = *(const bf16x8*)&lds[c + 8192 + ardB + 3 * 512];
    if (st) stageHalf(Asrc0, o, kN);
    __builtin_amdgcn_s_barrier();
    asm volatile("s_waitcnt lgkmcnt(0)" ::: "memory");
    __builtin_amdgcn_sched_barrier(0);
    __builtin_amdgcn_s_setprio(1);
#pragma unroll
    for (int n = 0; n < 4; ++n) {
      bf16x8 bb = (n == 0) ? b0 : (n == 1) ? b1 : (n == 2) ? b2 : b3;
      acc[0][n] = __builtin_amdgcn_mfma_f32_16x16x32_bf16(bb, a0, acc[0][n], 0, 0, 0);
      acc[1][n] = __builtin_amdgcn_mfma_f32_16x16x32_bf16(bb, a1, acc[1][n], 0, 0, 0);
      acc[2][n] = __builtin_amdgcn_mfma_f32_16x16x32_bf16(bb, a2, acc[2][n], 0, 0, 0);
      acc[3][n] = __builtin_amdgcn_mfma_f32_16x16x32_bf16(bb, a3, acc[3][n], 0, 0, 0);
    }
    __builtin_amdgcn_s_setprio(0);
    __builtin_amdgcn_s_barrier();

    // ---------- p1: A row-half 1 @k0 (4 reads, B carried); stage B_k0(next)
    a0 = *(const bf16x8*)&lds[c + 2048 + ardA + 0 * 512];
    a1 = *(const bf16x8*)&lds[c + 2048 + ardA + 1 * 512];
    a2 = *(const bf16x8*)&lds[c + 2048 + ardA + 2 * 512];
    a3 = *(const bf16x8*)&lds[c + 2048 + ardA + 3 * 512];
    if (st) stageHalf(Bsrc0, o + 8192, kN);
    __builtin_amdgcn_s_barrier();
    asm volatile("s_waitcnt lgkmcnt(0)" ::: "memory");
    __builtin_amdgcn_sched_barrier(0);
    __builtin_amdgcn_s_setprio(1);
#pragma unroll
    for (int n = 0; n < 4; ++n) {
      bf16x8 bb = (n == 0) ? b0 : (n == 1) ? b1 : (n == 2) ? b2 : b3;
      acc[4][n] = __builtin_amdgcn_mfma_f32_16x16x32_bf16(bb, a0, acc[4][n], 0, 0, 0);
      acc[5][n] = __builtin_amdgcn_mfma_f32_16x16x32_bf16(bb, a1, acc[5][n], 0, 0, 0);
      acc[6][n] = __builtin_amdgcn_mfma_f32_16x16x32_bf16(bb, a2, acc[6][n], 0, 0, 0);
      acc[7][n] = __builtin_amdgcn_mfma_f32_16x16x32_bf16(bb, a3, acc[7][n], 0, 0, 0);
    }
    __builtin_amdgcn_s_setprio(0);
    if (st) asm volatile("s_waitcnt vmcnt(4)" ::: "memory");
    else    asm volatile("s_waitcnt vmcnt(0)" ::: "memory");
    __builtin_amdgcn_s_barrier();

    // ---------- p2: A row-half 0 @k1 + all B @k1 (8 reads); stage A_k1(next)
    a0 = *(const bf16x8*)&lds[c + 16384 + ardA + 0 * 512];
    a1 = *(const bf16x8*)&lds[c + 16384 + ardA + 1 * 512];
    a2 = *(const bf16x8*)&lds[c + 16384 + ardA + 2 * 512];
    a3 = *(const bf16x8*)&lds[c + 16384 + ardA + 3 * 512];
    b0 = *(const bf16x8*)&lds[c + 24576 + ardB + 0 * 512];
    b1 = *(const bf16x8*)&lds[c + 24576 + ardB + 1 * 512];
    b2 = *(const bf16x8*)&lds[c + 24576 + ardB + 2 * 512];
    b3 = *(const bf16x8*)&lds[c + 24576 + ardB + 3 * 512];
    if (st) stageHalf(Asrc0, o + 16384, kN + 32);
    __builtin_amdgcn_s_barrier();
    asm volatile("s_waitcnt lgkmcnt(0)" ::: "memory");
    __builtin_amdgcn_sched_barrier(0);
    __builtin_amdgcn_s_setprio(1);
#pragma unroll
    for (int n = 0; n < 4; ++n) {
      bf16x8 bb = (n == 0) ? b0 : (n == 1) ? b1 : (n == 2) ? b2 : b3;
      acc[0][n] = __builtin_amdgcn_mfma_f32_16x16x32_bf16(bb, a0, acc[0][n], 0, 0, 0);
      acc[1][n] = __builtin_amdgcn_mfma_f32_16x16x32_bf16(bb, a1, acc[1][n], 0, 0, 0);
      acc[2][n] = __builtin_amdgcn_mfma_f32_16x16x32_bf16(bb, a2, acc[2][n], 0, 0, 0);
      acc[3][n] = __builtin_amdgcn_mfma_f32_16x16x32_bf16(bb, a3, acc[3][n], 0, 0, 0);
    }
    __builtin_amdgcn_s_setprio(0);
    __builtin_amdgcn_s_barrier();

    // ---------- p3: A row-half 1 @k1 (4 reads, B carried); stage B_k1(next)
    a0 = *(const bf16x8*)&lds[c + 18432 + ardA + 0 * 512];
    a1 = *(const bf16x8*)&lds[c + 18432 + ardA + 1 * 512];
    a2 = *(const bf16x8*)&lds[c + 18432 + ardA + 2 * 512];
    a3 = *(const bf16x8*)&lds[c + 18432 + ardA + 3 * 512];
    if (st) stageHalf(Bsrc0, o + 24576, kN + 32);
    __builtin_amdgcn_s_barrier();
    asm volatile("s_waitcnt lgkmcnt(0)" ::: "memory");
    __builtin_amdgcn_sched_barrier(0);
    __builtin_amdgcn_s_setprio(1);
#pragma unroll
    for (int n = 0; n < 4; ++n) {
      bf16x8 bb = (n == 0) ? b0 : (n == 1) ? b1 : (n == 2) ? b2 : b3;
      acc[4][n] = __builtin_amdgcn_mfma_f32_16x16x32_bf16(bb, a0, acc[4][n], 0, 0, 0);
      acc[5][n] = __builtin_amdgcn_mfma_f32_16x16x32_bf16(bb, a1, acc[5][n], 0, 0, 0);
      acc[6][n] = __builtin_amdgcn_mfma_f32_16x16x32_bf16(bb, a2, acc[6][n], 0, 0, 0);
      acc[7][n] = __builtin_amdgcn_mfma_f32_16x16x32_bf16(bb, a3, acc[7][n], 0, 0, 0);
    }
    __builtin_amdgcn_s_setprio(0);
    if (st) asm volatile("s_waitcnt vmcnt(4)" ::: "memory");
    __builtin_amdgcn_s_barrier();
  }

  // epilogue: bias + relu + packed bf16x4 (8B) stores (D^T layout:
  // fr = m-local row, kg*4+j = n-local col -> 4 consecutive output columns)
#pragma unroll
  for (int mm = 0; mm < 8; ++mm) {
    const int row = rowBase + wm * 128 + (mm >> 2) * 64 + (mm & 3) * 16 + fr;
#pragma unroll
    for (int n = 0; n < 4; ++n) {
      const int col0 = colBase + wn * 64 + n * 16 + kg * 4;
      ushort4 o;
      o.x = f2bf(fmaxf(acc[mm][n][0] + bias[col0 + 0], 0.f));
      o.y = f2bf(fmaxf(acc[mm][n][1] + bias[col0 + 1], 0.f));
      o.z = f2bf(fmaxf(acc[mm][n][2] + bias[col0 + 2], 0.f));
      o.w = f2bf(fmaxf(acc[mm][n][3] + bias[col0 + 3], 0.f));
      *reinterpret_cast<ushort4*>(&C[(size_t)row * N + col0]) = o;
    }
  }
}

// ---------------- final: h3[Bc][256] -> relu(h3*W4+b4) -> softmax(2) -> f32 out
__global__ void final_kernel(const u16* __restrict__ H3, const float* __restrict__ W4,
                             const float* __restrict__ b4, float* __restrict__ out, int M) {
  const int lane = threadIdx.x & 63;
  const int row  = blockIdx.x * 4 + (threadIdx.x >> 6);
  const ushort4 h = *reinterpret_cast<const ushort4*>(H3 + (size_t)row * 256 + lane * 4);
  const float x0 = bf2f(h.x), x1 = bf2f(h.y), x2 = bf2f(h.z), x3 = bf2f(h.w);
  const float2 w0 = *reinterpret_cast<const float2*>(W4 + (size_t)(lane * 4 + 0) * 2);
  const float2 w1 = *reinterpret_cast<const float2*>(W4 + (size_t)(lane * 4 + 1) * 2);
  const float2 w2 = *reinterpret_cast<const float2*>(W4 + (size_t)(lane * 4 + 2) * 2);
  const float2 w3 = *reinterpret_cast<const float2*>(W4 + (size_t)(lane * 4 + 3) * 2);
  float s0 = x0 * w0.x + x1 * w1.x + x2 * w2.x + x3 * w3.x;
  float s1 = x0 * w0.y + x1 * w1.y + x2 * w2.y + x3 * w3.y;
#pragma unroll
  for (int off = 32; off > 0; off >>= 1) {
    s0 += __shfl_xor(s0, off);
    s1 += __shfl_xor(s1, off);
  }
  if (lane == 0) {
    float z0 = fmaxf(s0 + b4[0], 0.f);
    float z1 = fmaxf(s1 + b4[1], 0.f);
    float mx = fmaxf(z0, z1);
    float e0 = __expf(z0 - mx), e1 = __expf(z1 - mx);
    float inv = 1.0f / (e0 + e1);
    out[(size_t)row * 2]     = e0 * inv;
    out[(size_t)row * 2 + 1] = e1 * inv;
  }
}

// ---------------- host side
extern "C" void kernel_launch(void* const* d_in, const int* in_sizes, int n_in,
                              void* d_out, int out_size, void* d_ws, size_t ws_size,
                              hipStream_t stream) {
  const float* W1 = (const float*)d_in[32];
  const float* b1 = (const float*)d_in[33];
  const float* W2 = (const float*)d_in[34];
  const float* b2 = (const float*)d_in[35];
  const float* W3 = (const float*)d_in[36];
  const float* b3 = (const float*)d_in[37];
  const float* W4 = (const float*)d_in[38];
  const float* b4 = (const float*)d_in[39];

  // host-side, non-stream, deterministic on every call
  (void)hipFuncSetAttribute(reinterpret_cast<const void*>(&gemm8<KPAD1>),
                            hipFuncAttributeMaxDynamicSharedMemorySize, 131072);
  (void)hipFuncSetAttribute(reinterpret_cast<const void*>(&gemm8<1024>),
                            hipFuncAttributeMaxDynamicSharedMemorySize, 131072);
  (void)hipFuncSetAttribute(reinterpret_cast<const void*>(&gemm8<512>),
                            hipFuncAttributeMaxDynamicSharedMemorySize, 131072);

  char* ws = (char*)d_ws;
  size_t off = 0;
  auto alloc = [&](size_t bytes) -> void* {
    void* p = ws + off;
    off += (bytes + 255) & ~(size_t)255;
    return p;
  };

  u16* W1t = (u16*)alloc((size_t)1024 * KPAD1 * 2);
  u16* W2t = (u16*)alloc((size_t)512 * 1024 * 2);
  u16* W3t = (u16*)alloc((size_t)256 * 512 * 2);
  const size_t fixed = off;

  // per-chunk: X (Bc x 1472) + H1 (Bc x 1024); H2/H3 alias X (dead after GEMM1)
  int nc = 64;
  const int cands[7] = {1, 2, 4, 8, 16, 32, 64};
  for (int ci = 0; ci < 7; ++ci) {
    size_t Bc = (size_t)B_TOTAL / cands[ci];
    size_t need = fixed + Bc * (KPAD1 + 1024) * 2 + 4096;
    if (need <= ws_size) { nc = cands[ci]; break; }
  }
  const int Bc = B_TOTAL / nc;

  u16* X  = (u16*)alloc((size_t)Bc * KPAD1 * 2);
  u16* H1 = (u16*)alloc((size_t)Bc * 1024 * 2);
  u16* H2 = X;                                    // Bc x 512, aliases X (X dead)
  u16* H3 = X + (size_t)Bc * 512;                 // Bc x 256, disjoint from H2

  wprep_kernel<<<(1024 * KPAD1 + 255) / 256, 256, 0, stream>>>(W1, W1t, 1424, 1024, KPAD1);
  wprep_kernel<<<(512 * 1024 + 255) / 256, 256, 0, stream>>>(W2, W2t, 1024, 512, 1024);
  wprep_kernel<<<(256 * 512 + 255) / 256, 256, 0, stream>>>(W3, W3t, 512, 256, 512);

  GatherArgs ga;
  for (int f = 0; f < 15; ++f) {
    ga.idx[f] = (const int*)d_in[2 * f];
    ga.E[f]   = (const float*)d_in[2 * f + 1];
  }
  ga.idx_u = (const int*)d_in[30];
  ga.E_u   = (const float*)d_in[31];

  const int gm = Bc / 256;
  for (int c = 0; c < nc; ++c) {
    gather_kernel<<<Bc / 4, 256, 0, stream>>>(ga, X, c * Bc);
    gemm8<KPAD1><<<gm * (1024 / 256), 512, 131072, stream>>>(X, W1t, b1, H1, 1024, gm);
    gemm8<1024><<<gm * (512 / 256), 512, 131072, stream>>>(H1, W2t, b2, H2, 512, gm);
    gemm8<512><<<gm * (256 / 256), 512, 131072, stream>>>(H2, W3t, b3, H3, 256, gm);
    final_kernel<<<Bc / 4, 256, 0, stream>>>(H3, W4, b4, (float*)d_out + (size_t)c * Bc * 2, Bc);
  }
}

// Round 11
// 515.607 us; speedup vs baseline: 1.0866x; 1.0866x over previous
//
#include <hip/hip_runtime.h>
#include <stdint.h>

typedef unsigned short u16;
typedef __attribute__((ext_vector_type(8))) __bf16 bf16x8;
typedef __attribute__((ext_vector_type(4))) float f32x4;

#define B_TOTAL 65536
#define KPAD1   1440   // 1424 padded to multiple of 32

__device__ __forceinline__ u16 f2bf(float f) {
  union { float f; uint32_t u; } v; v.f = f;
  uint32_t r = v.u + 0x7fffu + ((v.u >> 16) & 1u);
  return (u16)(r >> 16);
}
__device__ __forceinline__ float bf2f(u16 h) {
  union { uint32_t u; float f; } v; v.u = ((uint32_t)h) << 16;
  return v.f;
}

__device__ __forceinline__ void gload16(const void* g, void* lds) {
  __builtin_amdgcn_global_load_lds(
      (const __attribute__((address_space(1))) uint32_t*)g,
      (__attribute__((address_space(3))) uint32_t*)lds, 16, 0, 0);
}

// ---------------- weight prep: f32 [K][N] -> bf16 [N][Kpad] (transposed, zero-padded K)
__global__ void wprep_kernel(const float* __restrict__ W, u16* __restrict__ Wt,
                             int K, int N, int Kpad) {
  int o = blockIdx.x * 256 + threadIdx.x;
  if (o >= N * Kpad) return;
  int k = o % Kpad;
  int n = o / Kpad;
  float v = (k < K) ? W[(size_t)k * N + n] : 0.0f;
  Wt[o] = f2bf(v);
}

// ---------------- gather + concat -> X bf16 [Bc][1440]
struct GatherArgs {
  const int*   idx[15];
  const float* E[15];
  const int*   idx_u;
  const float* E_u;
};

constexpr int FDIM[15] = {128,128,128,16,16,96,144,64,80,64,48,144,96,16,144};
constexpr int FOFF[15] = {0,128,256,384,400,416,512,656,720,800,864,912,1056,1152,1168};

__global__ void gather_kernel(GatherArgs p, u16* __restrict__ X, int row_base) {
  const int lane = threadIdx.x & 63;
  const int row  = blockIdx.x * 4 + (threadIdx.x >> 6);
  const int grow = row_base + row;
  u16* xrow = X + (size_t)row * KPAD1;

#pragma unroll
  for (int f = 0; f < 15; ++f) {
    const int id = p.idx[f][grow];
    const float* src = p.E[f] + (size_t)id * FDIM[f];
    const int ng = FDIM[f] / 4;
    if (lane < ng) {
      const float4 v = *reinterpret_cast<const float4*>(src + lane * 4);
      ushort4 o;
      o.x = f2bf(v.x); o.y = f2bf(v.y); o.z = f2bf(v.z); o.w = f2bf(v.w);
      *reinterpret_cast<ushort4*>(xrow + FOFF[f] + lane * 4) = o;
    }
  }
  // userids mean-pool over 50, dim 112: lanes 0..27 take 4 cols each, 2-deep ILP
  const int* iu = p.idx_u + (size_t)grow * 50;
  if (lane < 28) {
    float4 s0 = {0.f, 0.f, 0.f, 0.f}, s1 = {0.f, 0.f, 0.f, 0.f};
#pragma unroll 5
    for (int j = 0; j < 50; j += 2) {
      const int i0 = iu[j];
      const int i1 = iu[j + 1];
      const float4 v0 = *reinterpret_cast<const float4*>(p.E_u + (size_t)i0 * 112 + lane * 4);
      const float4 v1 = *reinterpret_cast<const float4*>(p.E_u + (size_t)i1 * 112 + lane * 4);
      s0.x += v0.x; s0.y += v0.y; s0.z += v0.z; s0.w += v0.w;
      s1.x += v1.x; s1.y += v1.y; s1.z += v1.z; s1.w += v1.w;
    }
    const float inv = 1.0f / 50.0f;
    ushort4 o;
    o.x = f2bf((s0.x + s1.x) * inv);
    o.y = f2bf((s0.y + s1.y) * inv);
    o.z = f2bf((s0.z + s1.z) * inv);
    o.w = f2bf((s0.w + s1.w) * inv);
    *reinterpret_cast<ushort4*>(xrow + 1312 + lane * 4) = o;
  } else if (lane < 32) {
    ushort4 z; z.x = 0; z.y = 0; z.z = 0; z.w = 0;
    *reinterpret_cast<ushort4*>(xrow + 1424 + (lane - 28) * 4) = z;
  }
}

// ---------------- gemm8: 256x256 tile, BK=32, 3-buffer pipeline, swizzled LDS, free-run
// (R8 version — best measured: 113.5 us on GEMM1)
#define TILE_ELE 16384   // u16 elems per buffer (A 8192 + B 8192)

__global__ __launch_bounds__(512, 2) void gemm8(
    const u16* __restrict__ A, const u16* __restrict__ Wt,
    const float* __restrict__ bias, u16* __restrict__ C,
    int M, int N, int K, int gm) {
  extern __shared__ __align__(16) u16 lds[];
  const int tid  = threadIdx.x;
  const int w    = tid >> 6;
  const int lane = tid & 63;
  const int fr   = lane & 15;
  const int kg   = lane >> 4;
  const int wm   = w >> 2;      // 0..1
  const int wn   = w & 3;       // 0..3

  const int nwg = gridDim.x;
  const int q = nwg >> 3, r = nwg & 7;
  const int xcd = blockIdx.x & 7, lid = blockIdx.x >> 3;
  const int swz = (xcd < r) ? (xcd * (q + 1) + lid) : (r * (q + 1) + (xcd - r) * q + lid);
  const int bm = swz % gm, bn = swz / gm;
  const int rowBase = bm * 256, colBase = bn * 256;

  const int srow  = lane >> 2;
  const int sslot = (lane & 3) ^ ((lane >> 3) & 3);
  const u16* Asrc0 = A  + (size_t)(rowBase + w * 16 + srow) * K + sslot * 8;
  const u16* Bsrc0 = Wt + (size_t)(colBase + w * 16 + srow) * K + sslot * 8;
  const size_t rstep = (size_t)128 * K;

  const int NT = K / 32;

  f32x4 acc[8][4];
#pragma unroll
  for (int m = 0; m < 8; ++m)
#pragma unroll
    for (int n = 0; n < 4; ++n)
      acc[m][n] = f32x4{0.f, 0.f, 0.f, 0.f};

  const int aslot8 = (kg ^ ((fr >> 1) & 3)) * 8;
  const int ardA = (wm * 128 + fr) * 32 + aslot8;
  const int ardB = (wn * 64 + fr) * 32 + aslot8 + 8192;

  auto stage = [&](const u16* src0, int ldsElemBase, int kt) {
    const u16* s = src0 + (size_t)kt * 32;
    gload16(s,         &lds[ldsElemBase + w * 512]);
    gload16(s + rstep, &lds[ldsElemBase + w * 512 + 4096]);
  };

  stage(Asrc0, 0 * TILE_ELE,        0);
  stage(Bsrc0, 0 * TILE_ELE + 8192, 0);
  stage(Asrc0, 1 * TILE_ELE,        1);
  stage(Bsrc0, 1 * TILE_ELE + 8192, 1);

  for (int t = 0; t < NT; ++t) {
    const int cb = t % 3;
    const int sb = (t + 2) % 3;
    const bool dost = (t + 2) < NT;
    const int cA = cb * TILE_ELE;

    __builtin_amdgcn_sched_barrier(0);
    if (t < NT - 1) asm volatile("s_waitcnt vmcnt(4)" ::: "memory");
    else            asm volatile("s_waitcnt vmcnt(0)" ::: "memory");
    __builtin_amdgcn_s_barrier();
    __builtin_amdgcn_sched_barrier(0);

    bf16x8 a0 = *(const bf16x8*)&lds[cA + ardA + 0 * 512];
    bf16x8 a1 = *(const bf16x8*)&lds[cA + ardA + 1 * 512];
    bf16x8 a2 = *(const bf16x8*)&lds[cA + ardA + 2 * 512];
    bf16x8 a3 = *(const bf16x8*)&lds[cA + ardA + 3 * 512];
    bf16x8 b0 = *(const bf16x8*)&lds[cA + ardB + 0 * 512];
    bf16x8 b1 = *(const bf16x8*)&lds[cA + ardB + 1 * 512];
    bf16x8 b2 = *(const bf16x8*)&lds[cA + ardB + 2 * 512];
    bf16x8 b3 = *(const bf16x8*)&lds[cA + ardB + 3 * 512];
    bf16x8 c0 = *(const bf16x8*)&lds[cA + ardA + 2048 + 0 * 512];
    bf16x8 c1 = *(const bf16x8*)&lds[cA + ardA + 2048 + 1 * 512];
    bf16x8 c2 = *(const bf16x8*)&lds[cA + ardA + 2048 + 2 * 512];
    bf16x8 c3 = *(const bf16x8*)&lds[cA + ardA + 2048 + 3 * 512];
    if (dost) {
      stage(Asrc0, sb * TILE_ELE,        t + 2);
      stage(Bsrc0, sb * TILE_ELE + 8192, t + 2);
    }
#pragma unroll
    for (int n = 0; n < 4; ++n) {
      bf16x8 bf = (n == 0) ? b0 : (n == 1) ? b1 : (n == 2) ? b2 : b3;
      acc[0][n] = __builtin_amdgcn_mfma_f32_16x16x32_bf16(bf, a0, acc[0][n], 0, 0, 0);
      acc[1][n] = __builtin_amdgcn_mfma_f32_16x16x32_bf16(bf, a1, acc[1][n], 0, 0, 0);
      acc[2][n] = __builtin_amdgcn_mfma_f32_16x16x32_bf16(bf, a2, acc[2][n], 0, 0, 0);
      acc[3][n] = __builtin_amdgcn_mfma_f32_16x16x32_bf16(bf, a3, acc[3][n], 0, 0, 0);
      acc[4][n] = __builtin_amdgcn_mfma_f32_16x16x32_bf16(bf, c0, acc[4][n], 0, 0, 0);
      acc[5][n] = __builtin_amdgcn_mfma_f32_16x16x32_bf16(bf, c1, acc[5][n], 0, 0, 0);
      acc[6][n] = __builtin_amdgcn_mfma_f32_16x16x32_bf16(bf, c2, acc[6][n], 0, 0, 0);
      acc[7][n] = __builtin_amdgcn_mfma_f32_16x16x32_bf16(bf, c3, acc[7][n], 0, 0, 0);
    }
  }

#pragma unroll
  for (int mm = 0; mm < 8; ++mm) {
    const int row = rowBase + wm * 128 + (mm >> 2) * 64 + (mm & 3) * 16 + fr;
#pragma unroll
    for (int n = 0; n < 4; ++n) {
      const int col0 = colBase + wn * 64 + n * 16 + kg * 4;
      ushort4 o;
      o.x = f2bf(fmaxf(acc[mm][n][0] + bias[col0 + 0], 0.f));
      o.y = f2bf(fmaxf(acc[mm][n][1] + bias[col0 + 1], 0.f));
      o.z = f2bf(fmaxf(acc[mm][n][2] + bias[col0 + 2], 0.f));
      o.w = f2bf(fmaxf(acc[mm][n][3] + bias[col0 + 3], 0.f));
      *reinterpret_cast<ushort4*>(&C[(size_t)row * N + col0]) = o;
    }
  }
}

// ---------------- gemm3f: fused GEMM3 (128x256 tile, K=512) + W4 GEMV + softmax
// out[r][0..1] = softmax(relu( relu(H2[r]·W3^T + b3) · W4 + b4 ))
// Block: 512 thr = 8 waves (wm 2 x wn 4, 64x64 quadrants). One block-col (N=256)
// -> full h3 rows live in-block; no H3 materialization.
__global__ __launch_bounds__(512, 2) void gemm3f(
    const u16* __restrict__ A, const u16* __restrict__ Wt,
    const float* __restrict__ bias, const float* __restrict__ W4,
    const float* __restrict__ b4, float* __restrict__ out, int gm) {
  constexpr int K = 512, NT = 16;
  __shared__ __align__(16) u16 lds[2][12288];   // per buf: A[128][32] (4096) + B[256][32] (8192)
  __shared__ float w4s[512];
  __shared__ float zred[4][128][2];
  const int tid  = threadIdx.x;
  const int w    = tid >> 6;
  const int lane = tid & 63;
  const int fr   = lane & 15;
  const int kg   = lane >> 4;
  const int wm   = w >> 2;      // 0..1
  const int wn   = w & 3;       // 0..3

  const int nwg = gridDim.x;
  const int q = nwg >> 3, r = nwg & 7;
  const int xcd = blockIdx.x & 7, lid = blockIdx.x >> 3;
  const int swz = (xcd < r) ? (xcd * (q + 1) + lid) : (r * (q + 1) + (xcd - r) * q + lid);
  const int rowBase = swz * 128;

  if (tid < 512) w4s[tid] = W4[tid];

  // staging: A = 512 xfers (1/thread), B = 1024 xfers (2/thread)
  const int xslot = (tid & 3) ^ ((tid >> 3) & 3);
  const u16* Asrc  = A  + (size_t)(rowBase + (tid >> 2)) * K + xslot * 8;
  const u16* Bsrc0 = Wt + (size_t)(tid >> 2) * K + xslot * 8;           // cols 0..127
  const u16* Bsrc1 = Wt + (size_t)((tid >> 2) + 128) * K + xslot * 8;   // cols 128..255

  auto stage = [&](int buf, int kt) {
    const int ko = kt * 32;
    gload16(Asrc  + ko, &lds[buf][tid * 8]);
    gload16(Bsrc0 + ko, &lds[buf][4096 + tid * 8]);
    gload16(Bsrc1 + ko, &lds[buf][8192 + tid * 8]);
  };

  f32x4 acc[4][4];
#pragma unroll
  for (int m = 0; m < 4; ++m)
#pragma unroll
    for (int n = 0; n < 4; ++n)
      acc[m][n] = f32x4{0.f, 0.f, 0.f, 0.f};

  const int aslot8 = (kg ^ ((fr >> 1) & 3)) * 8;
  const int ardA = (wm * 64 + fr) * 32 + aslot8;           // + m*512
  const int ardB = 4096 + (wn * 64 + fr) * 32 + aslot8;    // + n*512

  stage(0, 0);
  stage(1, 1);

  for (int t = 0; t < NT; ++t) {
    const int cb = t & 1;
    if (t < NT - 1) asm volatile("s_waitcnt vmcnt(3)" ::: "memory");
    else            asm volatile("s_waitcnt vmcnt(0)" ::: "memory");
    __builtin_amdgcn_s_barrier();

    bf16x8 a0 = *(const bf16x8*)&lds[cb][ardA + 0 * 512];
    bf16x8 a1 = *(const bf16x8*)&lds[cb][ardA + 1 * 512];
    bf16x8 a2 = *(const bf16x8*)&lds[cb][ardA + 2 * 512];
    bf16x8 a3 = *(const bf16x8*)&lds[cb][ardA + 3 * 512];
    bf16x8 b0 = *(const bf16x8*)&lds[cb][ardB + 0 * 512];
    bf16x8 b1 = *(const bf16x8*)&lds[cb][ardB + 1 * 512];
    bf16x8 b2 = *(const bf16x8*)&lds[cb][ardB + 2 * 512];
    bf16x8 b3 = *(const bf16x8*)&lds[cb][ardB + 3 * 512];
    asm volatile("s_waitcnt lgkmcnt(0)" ::: "memory");
    __builtin_amdgcn_s_barrier();     // all waves' reads of buf cb drained
    if (t + 2 < NT) stage(cb, t + 2); // overwrite cb safely; consumers hold regs
    __builtin_amdgcn_sched_barrier(0);
    __builtin_amdgcn_s_setprio(1);
#pragma unroll
    for (int n = 0; n < 4; ++n) {
      bf16x8 bf = (n == 0) ? b0 : (n == 1) ? b1 : (n == 2) ? b2 : b3;
      acc[0][n] = __builtin_amdgcn_mfma_f32_16x16x32_bf16(bf, a0, acc[0][n], 0, 0, 0);
      acc[1][n] = __builtin_amdgcn_mfma_f32_16x16x32_bf16(bf, a1, acc[1][n], 0, 0, 0);
      acc[2][n] = __builtin_amdgcn_mfma_f32_16x16x32_bf16(bf, a2, acc[2][n], 0, 0, 0);
      acc[3][n] = __builtin_amdgcn_mfma_f32_16x16x32_bf16(bf, a3, acc[3][n], 0, 0, 0);
    }
    __builtin_amdgcn_s_setprio(0);
  }

  // fused epilogue: h3 = relu(acc + b3) in f32; z = h3·W4 partials per lane
  float z0[4] = {0.f, 0.f, 0.f, 0.f};
  float z1[4] = {0.f, 0.f, 0.f, 0.f};
#pragma unroll
  for (int n = 0; n < 4; ++n) {
    const int col0 = wn * 64 + n * 16 + kg * 4;
#pragma unroll
    for (int j = 0; j < 4; ++j) {
      const int c = col0 + j;
      const float bv = bias[c];
      const float w40 = w4s[c * 2];
      const float w41 = w4s[c * 2 + 1];
#pragma unroll
      for (int m = 0; m < 4; ++m) {
        const float h = fmaxf(acc[m][n][j] + bv, 0.f);
        z0[m] += h * w40;
        z1[m] += h * w41;
      }
    }
  }
  // reduce over kg (lanes ^16, ^32): full per-wave (wn) sums
#pragma unroll
  for (int m = 0; m < 4; ++m) {
    z0[m] += __shfl_xor(z0[m], 16); z0[m] += __shfl_xor(z0[m], 32);
    z1[m] += __shfl_xor(z1[m], 16); z1[m] += __shfl_xor(z1[m], 32);
  }
  if (kg == 0) {
#pragma unroll
    for (int m = 0; m < 4; ++m) {
      const int rr = wm * 64 + m * 16 + fr;
      zred[wn][rr][0] = z0[m];
      zred[wn][rr][1] = z1[m];
    }
  }
  __syncthreads();
  if (tid < 128) {
    const float s0 = zred[0][tid][0] + zred[1][tid][0] + zred[2][tid][0] + zred[3][tid][0];
    const float s1 = zred[0][tid][1] + zred[1][tid][1] + zred[2][tid][1] + zred[3][tid][1];
    const float zz0 = fmaxf(s0 + b4[0], 0.f);
    const float zz1 = fmaxf(s1 + b4[1], 0.f);
    const float mx = fmaxf(zz0, zz1);
    const float e0 = __expf(zz0 - mx), e1 = __expf(zz1 - mx);
    const float inv = 1.0f / (e0 + e1);
    out[(size_t)(rowBase + tid) * 2]     = e0 * inv;
    out[(size_t)(rowBase + tid) * 2 + 1] = e1 * inv;
  }
}

// ---------------- host side
extern "C" void kernel_launch(void* const* d_in, const int* in_sizes, int n_in,
                              void* d_out, int out_size, void* d_ws, size_t ws_size,
                              hipStream_t stream) {
  const float* W1 = (const float*)d_in[32];
  const float* b1 = (const float*)d_in[33];
  const float* W2 = (const float*)d_in[34];
  const float* b2 = (const float*)d_in[35];
  const float* W3 = (const float*)d_in[36];
  const float* b3 = (const float*)d_in[37];
  const float* W4 = (const float*)d_in[38];
  const float* b4 = (const float*)d_in[39];

  (void)hipFuncSetAttribute(reinterpret_cast<const void*>(&gemm8),
                            hipFuncAttributeMaxDynamicSharedMemorySize, 98304);

  char* ws = (char*)d_ws;
  size_t off = 0;
  auto alloc = [&](size_t bytes) -> void* {
    void* p = ws + off;
    off += (bytes + 255) & ~(size_t)255;
    return p;
  };

  u16* W1t = (u16*)alloc((size_t)1024 * KPAD1 * 2);
  u16* W2t = (u16*)alloc((size_t)512 * 1024 * 2);
  u16* W3t = (u16*)alloc((size_t)256 * 512 * 2);
  const size_t fixed = off;

  // per-chunk: X (Bc x 1440) + H1 (Bc x 1024); H2 aliases X (dead after GEMM1)
  int nc = 64;
  const int cands[7] = {1, 2, 4, 8, 16, 32, 64};
  for (int ci = 0; ci < 7; ++ci) {
    size_t Bc = (size_t)B_TOTAL / cands[ci];
    size_t need = fixed + Bc * (KPAD1 + 1024) * 2 + 4096;
    if (need <= ws_size) { nc = cands[ci]; break; }
  }
  const int Bc = B_TOTAL / nc;

  u16* X  = (u16*)alloc((size_t)Bc * KPAD1 * 2);
  u16* H1 = (u16*)alloc((size_t)Bc * 1024 * 2);
  u16* H2 = X;   // Bc x 512, aliases X (X dead after GEMM1)

  wprep_kernel<<<(1024 * KPAD1 + 255) / 256, 256, 0, stream>>>(W1, W1t, 1424, 1024, KPAD1);
  wprep_kernel<<<(512 * 1024 + 255) / 256, 256, 0, stream>>>(W2, W2t, 1024, 512, 1024);
  wprep_kernel<<<(256 * 512 + 255) / 256, 256, 0, stream>>>(W3, W3t, 512, 256, 512);

  GatherArgs ga;
  for (int f = 0; f < 15; ++f) {
    ga.idx[f] = (const int*)d_in[2 * f];
    ga.E[f]   = (const float*)d_in[2 * f + 1];
  }
  ga.idx_u = (const int*)d_in[30];
  ga.E_u   = (const float*)d_in[31];

  const int gm = Bc / 256;
  for (int c = 0; c < nc; ++c) {
    gather_kernel<<<Bc / 4, 256, 0, stream>>>(ga, X, c * Bc);
    gemm8<<<gm * (1024 / 256), 512, 98304, stream>>>(X, W1t, b1, H1, Bc, 1024, KPAD1, gm);
    gemm8<<<gm * (512 / 256), 512, 98304, stream>>>(H1, W2t, b2, H2, Bc, 512, 1024, gm);
    gemm3f<<<Bc / 128, 512, 0, stream>>>(H2, W3t, b3, W4, b4,
                                         (float*)d_out + (size_t)c * Bc * 2, Bc / 128);
  }
}

// Round 13
// 462.184 us; speedup vs baseline: 1.2122x; 1.1156x over previous
//
#include <hip/hip_runtime.h>
#include <stdint.h>

typedef unsigned short u16;
typedef __attribute__((ext_vector_type(8))) __bf16 bf16x8;
typedef __attribute__((ext_vector_type(4))) float f32x4;

#define B_TOTAL 65536
#define KPAD1   1440   // 1424 padded to multiple of 32

__device__ __forceinline__ u16 f2bf(float f) {
  union { float f; uint32_t u; } v; v.f = f;
  uint32_t r = v.u + 0x7fffu + ((v.u >> 16) & 1u);
  return (u16)(r >> 16);
}
__device__ __forceinline__ float bf2f(u16 h) {
  union { uint32_t u; float f; } v; v.u = ((uint32_t)h) << 16;
  return v.f;
}

__device__ __forceinline__ void gload16(const void* g, void* lds) {
  __builtin_amdgcn_global_load_lds(
      (const __attribute__((address_space(1))) uint32_t*)g,
      (__attribute__((address_space(3))) uint32_t*)lds, 16, 0, 0);
}

// ---------------- weight prep: f32 [K][N] -> bf16 [N][Kpad] (transposed, zero-padded K)
__global__ void wprep_kernel(const float* __restrict__ W, u16* __restrict__ Wt,
                             int K, int N, int Kpad) {
  int o = blockIdx.x * 256 + threadIdx.x;
  if (o >= N * Kpad) return;
  int k = o % Kpad;
  int n = o / Kpad;
  float v = (k < K) ? W[(size_t)k * N + n] : 0.0f;
  Wt[o] = f2bf(v);
}

// ---------------- gather + concat -> X bf16 [Bc][1440]
struct GatherArgs {
  const int*   idx[15];
  const float* E[15];
  const int*   idx_u;
  const float* E_u;
};

constexpr int FDIM[15] = {128,128,128,16,16,96,144,64,80,64,48,144,96,16,144};
constexpr int FOFF[15] = {0,128,256,384,400,416,512,656,720,800,864,912,1056,1152,1168};

__global__ void gather_kernel(GatherArgs p, u16* __restrict__ X, int row_base) {
  const int lane = threadIdx.x & 63;
  const int row  = blockIdx.x * 4 + (threadIdx.x >> 6);
  const int grow = row_base + row;
  u16* xrow = X + (size_t)row * KPAD1;

  // preload userids indices early: lane j (<50) holds iu[j]; ids fetched via shfl
  const int* iu = p.idx_u + (size_t)grow * 50;
  const int myid = (lane < 50) ? iu[lane] : 0;

#pragma unroll
  for (int f = 0; f < 15; ++f) {
    const int id = p.idx[f][grow];
    const float* src = p.E[f] + (size_t)id * FDIM[f];
    const int ng = FDIM[f] / 4;
    if (lane < ng) {
      const float4 v = *reinterpret_cast<const float4*>(src + lane * 4);
      ushort4 o;
      o.x = f2bf(v.x); o.y = f2bf(v.y); o.z = f2bf(v.z); o.w = f2bf(v.w);
      *reinterpret_cast<ushort4*>(xrow + FOFF[f] + lane * 4) = o;
    }
  }

  // userids mean-pool over 50, dim 112:
  //  - lane halves split the j-range (half 0: j 0..24, half 1: j 25..49)
  //  - cols: (lane&31)<28, 4 cols each
  //  - ids via __shfl of preloaded myid (no memory dep); 5-deep batched loads
  const int half = lane >> 5;
  const int c    = lane & 31;
  float4 s = {0.f, 0.f, 0.f, 0.f};
  if (c < 28) {
    const float* eu = p.E_u + c * 4;
    const int j0 = half * 25;
#pragma unroll
    for (int jb = 0; jb < 25; jb += 5) {
      float4 v0, v1, v2, v3, v4;
      {
        const int i0 = __shfl(myid, j0 + jb + 0);
        const int i1 = __shfl(myid, j0 + jb + 1);
        const int i2 = __shfl(myid, j0 + jb + 2);
        const int i3 = __shfl(myid, j0 + jb + 3);
        const int i4 = __shfl(myid, j0 + jb + 4);
        v0 = *reinterpret_cast<const float4*>(eu + (size_t)i0 * 112);
        v1 = *reinterpret_cast<const float4*>(eu + (size_t)i1 * 112);
        v2 = *reinterpret_cast<const float4*>(eu + (size_t)i2 * 112);
        v3 = *reinterpret_cast<const float4*>(eu + (size_t)i3 * 112);
        v4 = *reinterpret_cast<const float4*>(eu + (size_t)i4 * 112);
      }
      s.x += v0.x + v1.x + v2.x + v3.x + v4.x;
      s.y += v0.y + v1.y + v2.y + v3.y + v4.y;
      s.z += v0.z + v1.z + v2.z + v3.z + v4.z;
      s.w += v0.w + v1.w + v2.w + v3.w + v4.w;
    }
    // cross-half reduce (pairs lane L <-> L^32 are both active: same c)
    s.x += __shfl_xor(s.x, 32);
    s.y += __shfl_xor(s.y, 32);
    s.z += __shfl_xor(s.z, 32);
    s.w += __shfl_xor(s.w, 32);
    if (half == 0) {
      const float inv = 1.0f / 50.0f;
      ushort4 o;
      o.x = f2bf(s.x * inv);
      o.y = f2bf(s.y * inv);
      o.z = f2bf(s.z * inv);
      o.w = f2bf(s.w * inv);
      *reinterpret_cast<ushort4*>(xrow + 1312 + c * 4) = o;
    }
  } else if (half == 1) {
    // zero-pad cols 1424..1439 (4 lanes x 4 cols)
    ushort4 z; z.x = 0; z.y = 0; z.z = 0; z.w = 0;
    *reinterpret_cast<ushort4*>(xrow + 1424 + (c - 28) * 4) = z;
  }
}

// ---------------- gemm8: 256x256 tile, BK=32, 3-buffer pipeline, swizzled LDS, free-run
// (R8 version — best measured: 113.5 us on GEMM1)
#define TILE_ELE 16384   // u16 elems per buffer (A 8192 + B 8192)

__global__ __launch_bounds__(512, 2) void gemm8(
    const u16* __restrict__ A, const u16* __restrict__ Wt,
    const float* __restrict__ bias, u16* __restrict__ C,
    int M, int N, int K, int gm) {
  extern __shared__ __align__(16) u16 lds[];
  const int tid  = threadIdx.x;
  const int w    = tid >> 6;
  const int lane = tid & 63;
  const int fr   = lane & 15;
  const int kg   = lane >> 4;
  const int wm   = w >> 2;      // 0..1
  const int wn   = w & 3;       // 0..3

  const int nwg = gridDim.x;
  const int q = nwg >> 3, r = nwg & 7;
  const int xcd = blockIdx.x & 7, lid = blockIdx.x >> 3;
  const int swz = (xcd < r) ? (xcd * (q + 1) + lid) : (r * (q + 1) + (xcd - r) * q + lid);
  const int bm = swz % gm, bn = swz / gm;
  const int rowBase = bm * 256, colBase = bn * 256;

  const int srow  = lane >> 2;
  const int sslot = (lane & 3) ^ ((lane >> 3) & 3);
  const u16* Asrc0 = A  + (size_t)(rowBase + w * 16 + srow) * K + sslot * 8;
  const u16* Bsrc0 = Wt + (size_t)(colBase + w * 16 + srow) * K + sslot * 8;
  const size_t rstep = (size_t)128 * K;

  const int NT = K / 32;

  f32x4 acc[8][4];
#pragma unroll
  for (int m = 0; m < 8; ++m)
#pragma unroll
    for (int n = 0; n < 4; ++n)
      acc[m][n] = f32x4{0.f, 0.f, 0.f, 0.f};

  const int aslot8 = (kg ^ ((fr >> 1) & 3)) * 8;
  const int ardA = (wm * 128 + fr) * 32 + aslot8;
  const int ardB = (wn * 64 + fr) * 32 + aslot8 + 8192;

  auto stage = [&](const u16* src0, int ldsElemBase, int kt) {
    const u16* s = src0 + (size_t)kt * 32;
    gload16(s,         &lds[ldsElemBase + w * 512]);
    gload16(s + rstep, &lds[ldsElemBase + w * 512 + 4096]);
  };

  stage(Asrc0, 0 * TILE_ELE,        0);
  stage(Bsrc0, 0 * TILE_ELE + 8192, 0);
  stage(Asrc0, 1 * TILE_ELE,        1);
  stage(Bsrc0, 1 * TILE_ELE + 8192, 1);

  for (int t = 0; t < NT; ++t) {
    const int cb = t % 3;
    const int sb = (t + 2) % 3;
    const bool dost = (t + 2) < NT;
    const int cA = cb * TILE_ELE;

    __builtin_amdgcn_sched_barrier(0);
    if (t < NT - 1) asm volatile("s_waitcnt vmcnt(4)" ::: "memory");
    else            asm volatile("s_waitcnt vmcnt(0)" ::: "memory");
    __builtin_amdgcn_s_barrier();
    __builtin_amdgcn_sched_barrier(0);

    bf16x8 a0 = *(const bf16x8*)&lds[cA + ardA + 0 * 512];
    bf16x8 a1 = *(const bf16x8*)&lds[cA + ardA + 1 * 512];
    bf16x8 a2 = *(const bf16x8*)&lds[cA + ardA + 2 * 512];
    bf16x8 a3 = *(const bf16x8*)&lds[cA + ardA + 3 * 512];
    bf16x8 b0 = *(const bf16x8*)&lds[cA + ardB + 0 * 512];
    bf16x8 b1 = *(const bf16x8*)&lds[cA + ardB + 1 * 512];
    bf16x8 b2 = *(const bf16x8*)&lds[cA + ardB + 2 * 512];
    bf16x8 b3 = *(const bf16x8*)&lds[cA + ardB + 3 * 512];
    bf16x8 c0 = *(const bf16x8*)&lds[cA + ardA + 2048 + 0 * 512];
    bf16x8 c1 = *(const bf16x8*)&lds[cA + ardA + 2048 + 1 * 512];
    bf16x8 c2 = *(const bf16x8*)&lds[cA + ardA + 2048 + 2 * 512];
    bf16x8 c3 = *(const bf16x8*)&lds[cA + ardA + 2048 + 3 * 512];
    if (dost) {
      stage(Asrc0, sb * TILE_ELE,        t + 2);
      stage(Bsrc0, sb * TILE_ELE + 8192, t + 2);
    }
#pragma unroll
    for (int n = 0; n < 4; ++n) {
      bf16x8 bf = (n == 0) ? b0 : (n == 1) ? b1 : (n == 2) ? b2 : b3;
      acc[0][n] = __builtin_amdgcn_mfma_f32_16x16x32_bf16(bf, a0, acc[0][n], 0, 0, 0);
      acc[1][n] = __builtin_amdgcn_mfma_f32_16x16x32_bf16(bf, a1, acc[1][n], 0, 0, 0);
      acc[2][n] = __builtin_amdgcn_mfma_f32_16x16x32_bf16(bf, a2, acc[2][n], 0, 0, 0);
      acc[3][n] = __builtin_amdgcn_mfma_f32_16x16x32_bf16(bf, a3, acc[3][n], 0, 0, 0);
      acc[4][n] = __builtin_amdgcn_mfma_f32_16x16x32_bf16(bf, c0, acc[4][n], 0, 0, 0);
      acc[5][n] = __builtin_amdgcn_mfma_f32_16x16x32_bf16(bf, c1, acc[5][n], 0, 0, 0);
      acc[6][n] = __builtin_amdgcn_mfma_f32_16x16x32_bf16(bf, c2, acc[6][n], 0, 0, 0);
      acc[7][n] = __builtin_amdgcn_mfma_f32_16x16x32_bf16(bf, c3, acc[7][n], 0, 0, 0);
    }
  }

#pragma unroll
  for (int mm = 0; mm < 8; ++mm) {
    const int row = rowBase + wm * 128 + (mm >> 2) * 64 + (mm & 3) * 16 + fr;
#pragma unroll
    for (int n = 0; n < 4; ++n) {
      const int col0 = colBase + wn * 64 + n * 16 + kg * 4;
      ushort4 o;
      o.x = f2bf(fmaxf(acc[mm][n][0] + bias[col0 + 0], 0.f));
      o.y = f2bf(fmaxf(acc[mm][n][1] + bias[col0 + 1], 0.f));
      o.z = f2bf(fmaxf(acc[mm][n][2] + bias[col0 + 2], 0.f));
      o.w = f2bf(fmaxf(acc[mm][n][3] + bias[col0 + 3], 0.f));
      *reinterpret_cast<ushort4*>(&C[(size_t)row * N + col0]) = o;
    }
  }
}

// ---------------- gemm3f: fused GEMM3 (128x256 tile, K=512) + W4 GEMV + softmax
__global__ __launch_bounds__(512, 2) void gemm3f(
    const u16* __restrict__ A, const u16* __restrict__ Wt,
    const float* __restrict__ bias, const float* __restrict__ W4,
    const float* __restrict__ b4, float* __restrict__ out, int gm) {
  constexpr int K = 512, NT = 16;
  __shared__ __align__(16) u16 lds[2][12288];   // per buf: A[128][32] (4096) + B[256][32] (8192)
  __shared__ float w4s[512];
  __shared__ float zred[4][128][2];
  const int tid  = threadIdx.x;
  const int w    = tid >> 6;
  const int lane = tid & 63;
  const int fr   = lane & 15;
  const int kg   = lane >> 4;
  const int wm   = w >> 2;      // 0..1
  const int wn   = w & 3;       // 0..3

  const int nwg = gridDim.x;
  const int q = nwg >> 3, r = nwg & 7;
  const int xcd = blockIdx.x & 7, lid = blockIdx.x >> 3;
  const int swz = (xcd < r) ? (xcd * (q + 1) + lid) : (r * (q + 1) + (xcd - r) * q + lid);
  const int rowBase = swz * 128;

  if (tid < 512) w4s[tid] = W4[tid];

  const int xslot = (tid & 3) ^ ((tid >> 3) & 3);
  const u16* Asrc  = A  + (size_t)(rowBase + (tid >> 2)) * K + xslot * 8;
  const u16* Bsrc0 = Wt + (size_t)(tid >> 2) * K + xslot * 8;           // cols 0..127
  const u16* Bsrc1 = Wt + (size_t)((tid >> 2) + 128) * K + xslot * 8;   // cols 128..255

  auto stage = [&](int buf, int kt) {
    const int ko = kt * 32;
    gload16(Asrc  + ko, &lds[buf][tid * 8]);
    gload16(Bsrc0 + ko, &lds[buf][4096 + tid * 8]);
    gload16(Bsrc1 + ko, &lds[buf][8192 + tid * 8]);
  };

  f32x4 acc[4][4];
#pragma unroll
  for (int m = 0; m < 4; ++m)
#pragma unroll
    for (int n = 0; n < 4; ++n)
      acc[m][n] = f32x4{0.f, 0.f, 0.f, 0.f};

  const int aslot8 = (kg ^ ((fr >> 1) & 3)) * 8;
  const int ardA = (wm * 64 + fr) * 32 + aslot8;           // + m*512
  const int ardB = 4096 + (wn * 64 + fr) * 32 + aslot8;    // + n*512

  stage(0, 0);
  stage(1, 1);

  for (int t = 0; t < NT; ++t) {
    const int cb = t & 1;
    if (t < NT - 1) asm volatile("s_waitcnt vmcnt(3)" ::: "memory");
    else            asm volatile("s_waitcnt vmcnt(0)" ::: "memory");
    __builtin_amdgcn_s_barrier();

    bf16x8 a0 = *(const bf16x8*)&lds[cb][ardA + 0 * 512];
    bf16x8 a1 = *(const bf16x8*)&lds[cb][ardA + 1 * 512];
    bf16x8 a2 = *(const bf16x8*)&lds[cb][ardA + 2 * 512];
    bf16x8 a3 = *(const bf16x8*)&lds[cb][ardA + 3 * 512];
    bf16x8 b0 = *(const bf16x8*)&lds[cb][ardB + 0 * 512];
    bf16x8 b1 = *(const bf16x8*)&lds[cb][ardB + 1 * 512];
    bf16x8 b2 = *(const bf16x8*)&lds[cb][ardB + 2 * 512];
    bf16x8 b3 = *(const bf16x8*)&lds[cb][ardB + 3 * 512];
    asm volatile("s_waitcnt lgkmcnt(0)" ::: "memory");
    __builtin_amdgcn_s_barrier();     // all waves' reads of buf cb drained
    if (t + 2 < NT) stage(cb, t + 2); // overwrite cb safely; consumers hold regs
    __builtin_amdgcn_sched_barrier(0);
    __builtin_amdgcn_s_setprio(1);
#pragma unroll
    for (int n = 0; n < 4; ++n) {
      bf16x8 bf = (n == 0) ? b0 : (n == 1) ? b1 : (n == 2) ? b2 : b3;
      acc[0][n] = __builtin_amdgcn_mfma_f32_16x16x32_bf16(bf, a0, acc[0][n], 0, 0, 0);
      acc[1][n] = __builtin_amdgcn_mfma_f32_16x16x32_bf16(bf, a1, acc[1][n], 0, 0, 0);
      acc[2][n] = __builtin_amdgcn_mfma_f32_16x16x32_bf16(bf, a2, acc[2][n], 0, 0, 0);
      acc[3][n] = __builtin_amdgcn_mfma_f32_16x16x32_bf16(bf, a3, acc[3][n], 0, 0, 0);
    }
    __builtin_amdgcn_s_setprio(0);
  }

  float z0[4] = {0.f, 0.f, 0.f, 0.f};
  float z1[4] = {0.f, 0.f, 0.f, 0.f};
#pragma unroll
  for (int n = 0; n < 4; ++n) {
    const int col0 = wn * 64 + n * 16 + kg * 4;
#pragma unroll
    for (int j = 0; j < 4; ++j) {
      const int c = col0 + j;
      const float bv = bias[c];
      const float w40 = w4s[c * 2];
      const float w41 = w4s[c * 2 + 1];
#pragma unroll
      for (int m = 0; m < 4; ++m) {
        const float h = fmaxf(acc[m][n][j] + bv, 0.f);
        z0[m] += h * w40;
        z1[m] += h * w41;
      }
    }
  }
#pragma unroll
  for (int m = 0; m < 4; ++m) {
    z0[m] += __shfl_xor(z0[m], 16); z0[m] += __shfl_xor(z0[m], 32);
    z1[m] += __shfl_xor(z1[m], 16); z1[m] += __shfl_xor(z1[m], 32);
  }
  if (kg == 0) {
#pragma unroll
    for (int m = 0; m < 4; ++m) {
      const int rr = wm * 64 + m * 16 + fr;
      zred[wn][rr][0] = z0[m];
      zred[wn][rr][1] = z1[m];
    }
  }
  __syncthreads();
  if (tid < 128) {
    const float s0 = zred[0][tid][0] + zred[1][tid][0] + zred[2][tid][0] + zred[3][tid][0];
    const float s1 = zred[0][tid][1] + zred[1][tid][1] + zred[2][tid][1] + zred[3][tid][1];
    const float zz0 = fmaxf(s0 + b4[0], 0.f);
    const float zz1 = fmaxf(s1 + b4[1], 0.f);
    const float mx = fmaxf(zz0, zz1);
    const float e0 = __expf(zz0 - mx), e1 = __expf(zz1 - mx);
    const float inv = 1.0f / (e0 + e1);
    out[(size_t)(rowBase + tid) * 2]     = e0 * inv;
    out[(size_t)(rowBase + tid) * 2 + 1] = e1 * inv;
  }
}

// ---------------- host side
extern "C" void kernel_launch(void* const* d_in, const int* in_sizes, int n_in,
                              void* d_out, int out_size, void* d_ws, size_t ws_size,
                              hipStream_t stream) {
  const float* W1 = (const float*)d_in[32];
  const float* b1 = (const float*)d_in[33];
  const float* W2 = (const float*)d_in[34];
  const float* b2 = (const float*)d_in[35];
  const float* W3 = (const float*)d_in[36];
  const float* b3 = (const float*)d_in[37];
  const float* W4 = (const float*)d_in[38];
  const float* b4 = (const float*)d_in[39];

  (void)hipFuncSetAttribute(reinterpret_cast<const void*>(&gemm8),
                            hipFuncAttributeMaxDynamicSharedMemorySize, 98304);

  char* ws = (char*)d_ws;
  size_t off = 0;
  auto alloc = [&](size_t bytes) -> void* {
    void* p = ws + off;
    off += (bytes + 255) & ~(size_t)255;
    return p;
  };

  u16* W1t = (u16*)alloc((size_t)1024 * KPAD1 * 2);
  u16* W2t = (u16*)alloc((size_t)512 * 1024 * 2);
  u16* W3t = (u16*)alloc((size_t)256 * 512 * 2);
  const size_t fixed = off;

  // per-chunk: X (Bc x 1440) + H1 (Bc x 1024); H2 aliases X (dead after GEMM1)
  int nc = 64;
  const int cands[7] = {1, 2, 4, 8, 16, 32, 64};
  for (int ci = 0; ci < 7; ++ci) {
    size_t Bc = (size_t)B_TOTAL / cands[ci];
    size_t need = fixed + Bc * (KPAD1 + 1024) * 2 + 4096;
    if (need <= ws_size) { nc = cands[ci]; break; }
  }
  const int Bc = B_TOTAL / nc;

  u16* X  = (u16*)alloc((size_t)Bc * KPAD1 * 2);
  u16* H1 = (u16*)alloc((size_t)Bc * 1024 * 2);
  u16* H2 = X;   // Bc x 512, aliases X (X dead after GEMM1)

  wprep_kernel<<<(1024 * KPAD1 + 255) / 256, 256, 0, stream>>>(W1, W1t, 1424, 1024, KPAD1);
  wprep_kernel<<<(512 * 1024 + 255) / 256, 256, 0, stream>>>(W2, W2t, 1024, 512, 1024);
  wprep_kernel<<<(256 * 512 + 255) / 256, 256, 0, stream>>>(W3, W3t, 512, 256, 512);

  GatherArgs ga;
  for (int f = 0; f < 15; ++f) {
    ga.idx[f] = (const int*)d_in[2 * f];
    ga.E[f]   = (const float*)d_in[2 * f + 1];
  }
  ga.idx_u = (const int*)d_in[30];
  ga.E_u   = (const float*)d_in[31];

  const int gm = Bc / 256;
  for (int c = 0; c < nc; ++c) {
    gather_kernel<<<Bc / 4, 256, 0, stream>>>(ga, X, c * Bc);
    gemm8<<<gm * (1024 / 256), 512, 98304, stream>>>(X, W1t, b1, H1, Bc, 1024, KPAD1, gm);
    gemm8<<<gm * (512 / 256), 512, 98304, stream>>>(H1, W2t, b2, H2, Bc, 512, 1024, gm);
    gemm3f<<<Bc / 128, 512, 0, stream>>>(H2, W3t, b3, W4, b4,
                                         (float*)d_out + (size_t)c * Bc * 2, Bc / 128);
  }
}

// Round 14
// 460.142 us; speedup vs baseline: 1.2176x; 1.0044x over previous
//
#include <hip/hip_runtime.h>
#include <stdint.h>

typedef unsigned short u16;
typedef __attribute__((ext_vector_type(8))) __bf16 bf16x8;
typedef __attribute__((ext_vector_type(4))) float f32x4;

#define B_TOTAL 65536
#define KPAD1   1440   // 1424 padded to multiple of 32

__device__ __forceinline__ u16 f2bf(float f) {
  union { float f; uint32_t u; } v; v.f = f;
  uint32_t r = v.u + 0x7fffu + ((v.u >> 16) & 1u);
  return (u16)(r >> 16);
}
__device__ __forceinline__ float bf2f(u16 h) {
  union { uint32_t u; float f; } v; v.u = ((uint32_t)h) << 16;
  return v.f;
}

__device__ __forceinline__ void gload16(const void* g, void* lds) {
  __builtin_amdgcn_global_load_lds(
      (const __attribute__((address_space(1))) uint32_t*)g,
      (__attribute__((address_space(3))) uint32_t*)lds, 16, 0, 0);
}

// ---------------- weight prep: f32 [K][N] -> bf16 [N][Kpad] (transposed, zero-padded K)
__global__ void wprep_kernel(const float* __restrict__ W, u16* __restrict__ Wt,
                             int K, int N, int Kpad) {
  int o = blockIdx.x * 256 + threadIdx.x;
  if (o >= N * Kpad) return;
  int k = o % Kpad;
  int n = o / Kpad;
  float v = (k < K) ? W[(size_t)k * N + n] : 0.0f;
  Wt[o] = f2bf(v);
}

// ---------------- gather + concat -> X bf16 [Bc][1440]
struct GatherArgs {
  const int*   idx[15];
  const float* E[15];
  const int*   idx_u;
  const float* E_u;
};

constexpr int FDIM[15] = {128,128,128,16,16,96,144,64,80,64,48,144,96,16,144};
constexpr int FOFF[15] = {0,128,256,384,400,416,512,656,720,800,864,912,1056,1152,1168};

__global__ void gather_kernel(GatherArgs p, u16* __restrict__ X, int row_base) {
  const int lane = threadIdx.x & 63;
  const int row  = blockIdx.x * 4 + (threadIdx.x >> 6);
  const int grow = row_base + row;
  u16* xrow = X + (size_t)row * KPAD1;

  // preload userids indices early: lane j (<50) holds iu[j]; ids fetched via shfl
  const int* iu = p.idx_u + (size_t)grow * 50;
  const int myid = (lane < 50) ? iu[lane] : 0;

#pragma unroll
  for (int f = 0; f < 15; ++f) {
    const int id = p.idx[f][grow];
    const float* src = p.E[f] + (size_t)id * FDIM[f];
    const int ng = FDIM[f] / 4;
    if (lane < ng) {
      const float4 v = *reinterpret_cast<const float4*>(src + lane * 4);
      ushort4 o;
      o.x = f2bf(v.x); o.y = f2bf(v.y); o.z = f2bf(v.z); o.w = f2bf(v.w);
      *reinterpret_cast<ushort4*>(xrow + FOFF[f] + lane * 4) = o;
    }
  }

  // userids mean-pool over 50, dim 112: halves split j-range; shfl-broadcast ids
  const int half = lane >> 5;
  const int c    = lane & 31;
  float4 s = {0.f, 0.f, 0.f, 0.f};
  if (c < 28) {
    const float* eu = p.E_u + c * 4;
    const int j0 = half * 25;
#pragma unroll
    for (int jb = 0; jb < 25; jb += 5) {
      float4 v0, v1, v2, v3, v4;
      {
        const int i0 = __shfl(myid, j0 + jb + 0);
        const int i1 = __shfl(myid, j0 + jb + 1);
        const int i2 = __shfl(myid, j0 + jb + 2);
        const int i3 = __shfl(myid, j0 + jb + 3);
        const int i4 = __shfl(myid, j0 + jb + 4);
        v0 = *reinterpret_cast<const float4*>(eu + (size_t)i0 * 112);
        v1 = *reinterpret_cast<const float4*>(eu + (size_t)i1 * 112);
        v2 = *reinterpret_cast<const float4*>(eu + (size_t)i2 * 112);
        v3 = *reinterpret_cast<const float4*>(eu + (size_t)i3 * 112);
        v4 = *reinterpret_cast<const float4*>(eu + (size_t)i4 * 112);
      }
      s.x += v0.x + v1.x + v2.x + v3.x + v4.x;
      s.y += v0.y + v1.y + v2.y + v3.y + v4.y;
      s.z += v0.z + v1.z + v2.z + v3.z + v4.z;
      s.w += v0.w + v1.w + v2.w + v3.w + v4.w;
    }
    s.x += __shfl_xor(s.x, 32);
    s.y += __shfl_xor(s.y, 32);
    s.z += __shfl_xor(s.z, 32);
    s.w += __shfl_xor(s.w, 32);
    if (half == 0) {
      const float inv = 1.0f / 50.0f;
      ushort4 o;
      o.x = f2bf(s.x * inv);
      o.y = f2bf(s.y * inv);
      o.z = f2bf(s.z * inv);
      o.w = f2bf(s.w * inv);
      *reinterpret_cast<ushort4*>(xrow + 1312 + c * 4) = o;
    }
  } else if (half == 1) {
    ushort4 z; z.x = 0; z.y = 0; z.z = 0; z.w = 0;
    *reinterpret_cast<ushort4*>(xrow + 1424 + (c - 28) * 4) = z;
  }
}

// ---------------- gemm8: 256x256 tile, BK=32, 2-buffer (64KB) free-run pipeline
// Changes vs R8-best: (1) 2 LDS buffers -> 64KB -> 2 blocks/CU (4 waves/SIMD);
// (2) bn-fast XCD swizzle so same-XCD blocks share the A row-panel (cuts the
// 2x A over-fetch seen as FETCH 194MB vs ideal 97MB).
// Ledger: stage(t+1) issued right after barrier(t); vmcnt(0) at each boundary
// retires exactly those 4 loads. Buffer (t+1)&1 was last read in tile t-1;
// every wave's t-1 ds_reads drained (data-dep lgkm before its MFMAs) before
// it passed barrier(t) -> overwrite is race-free.
#define TILE_ELE 16384   // u16 elems per buffer (A 8192 + B 8192)

__global__ __launch_bounds__(512, 2) void gemm8(
    const u16* __restrict__ A, const u16* __restrict__ Wt,
    const float* __restrict__ bias, u16* __restrict__ C,
    int M, int N, int K, int gm) {
  extern __shared__ __align__(16) u16 lds[];
  const int tid  = threadIdx.x;
  const int w    = tid >> 6;
  const int lane = tid & 63;
  const int fr   = lane & 15;
  const int kg   = lane >> 4;
  const int wm   = w >> 2;      // 0..1
  const int wn   = w & 3;       // 0..3

  // bijective XCD swizzle; bn-FAST so consecutive same-XCD blocks share A panel
  const int nwg = gridDim.x;
  const int q = nwg >> 3, r = nwg & 7;
  const int xcd = blockIdx.x & 7, lid = blockIdx.x >> 3;
  const int swz = (xcd < r) ? (xcd * (q + 1) + lid) : (r * (q + 1) + (xcd - r) * q + lid);
  const int gn = N >> 8;
  const int bn = swz % gn, bm = swz / gn;
  const int rowBase = bm * 256, colBase = bn * 256;

  const int srow  = lane >> 2;
  const int sslot = (lane & 3) ^ ((lane >> 3) & 3);
  const u16* Asrc0 = A  + (size_t)(rowBase + w * 16 + srow) * K + sslot * 8;
  const u16* Bsrc0 = Wt + (size_t)(colBase + w * 16 + srow) * K + sslot * 8;
  const size_t rstep = (size_t)128 * K;

  const int NT = K / 32;

  f32x4 acc[8][4];
#pragma unroll
  for (int m = 0; m < 8; ++m)
#pragma unroll
    for (int n = 0; n < 4; ++n)
      acc[m][n] = f32x4{0.f, 0.f, 0.f, 0.f};

  const int aslot8 = (kg ^ ((fr >> 1) & 3)) * 8;
  const int ardA = (wm * 128 + fr) * 32 + aslot8;
  const int ardB = (wn * 64 + fr) * 32 + aslot8 + 8192;

  auto stage = [&](const u16* src0, int ldsElemBase, int kt) {
    const u16* s = src0 + (size_t)kt * 32;
    gload16(s,         &lds[ldsElemBase + w * 512]);
    gload16(s + rstep, &lds[ldsElemBase + w * 512 + 4096]);
  };

  // prologue: stage tile 0 into buf 0
  stage(Asrc0, 0,        0);
  stage(Bsrc0, 0 + 8192, 0);

  for (int t = 0; t < NT; ++t) {
    const int cA = (t & 1) * TILE_ELE;
    const int sA = ((t + 1) & 1) * TILE_ELE;
    const bool dost = (t + 1) < NT;

    // boundary: tile t's 4 loads are the only outstanding stage ops
    __builtin_amdgcn_sched_barrier(0);
    asm volatile("s_waitcnt vmcnt(0)" ::: "memory");
    __builtin_amdgcn_s_barrier();
    __builtin_amdgcn_sched_barrier(0);

    if (dost) {
      stage(Asrc0, sA,        t + 1);
      stage(Bsrc0, sA + 8192, t + 1);
    }

    bf16x8 a0 = *(const bf16x8*)&lds[cA + ardA + 0 * 512];
    bf16x8 a1 = *(const bf16x8*)&lds[cA + ardA + 1 * 512];
    bf16x8 a2 = *(const bf16x8*)&lds[cA + ardA + 2 * 512];
    bf16x8 a3 = *(const bf16x8*)&lds[cA + ardA + 3 * 512];
    bf16x8 b0 = *(const bf16x8*)&lds[cA + ardB + 0 * 512];
    bf16x8 b1 = *(const bf16x8*)&lds[cA + ardB + 1 * 512];
    bf16x8 b2 = *(const bf16x8*)&lds[cA + ardB + 2 * 512];
    bf16x8 b3 = *(const bf16x8*)&lds[cA + ardB + 3 * 512];
    bf16x8 c0 = *(const bf16x8*)&lds[cA + ardA + 2048 + 0 * 512];
    bf16x8 c1 = *(const bf16x8*)&lds[cA + ardA + 2048 + 1 * 512];
    bf16x8 c2 = *(const bf16x8*)&lds[cA + ardA + 2048 + 2 * 512];
    bf16x8 c3 = *(const bf16x8*)&lds[cA + ardA + 2048 + 3 * 512];
#pragma unroll
    for (int n = 0; n < 4; ++n) {
      bf16x8 bf = (n == 0) ? b0 : (n == 1) ? b1 : (n == 2) ? b2 : b3;
      acc[0][n] = __builtin_amdgcn_mfma_f32_16x16x32_bf16(bf, a0, acc[0][n], 0, 0, 0);
      acc[1][n] = __builtin_amdgcn_mfma_f32_16x16x32_bf16(bf, a1, acc[1][n], 0, 0, 0);
      acc[2][n] = __builtin_amdgcn_mfma_f32_16x16x32_bf16(bf, a2, acc[2][n], 0, 0, 0);
      acc[3][n] = __builtin_amdgcn_mfma_f32_16x16x32_bf16(bf, a3, acc[3][n], 0, 0, 0);
      acc[4][n] = __builtin_amdgcn_mfma_f32_16x16x32_bf16(bf, c0, acc[4][n], 0, 0, 0);
      acc[5][n] = __builtin_amdgcn_mfma_f32_16x16x32_bf16(bf, c1, acc[5][n], 0, 0, 0);
      acc[6][n] = __builtin_amdgcn_mfma_f32_16x16x32_bf16(bf, c2, acc[6][n], 0, 0, 0);
      acc[7][n] = __builtin_amdgcn_mfma_f32_16x16x32_bf16(bf, c3, acc[7][n], 0, 0, 0);
    }
  }

  // epilogue: bias + relu + packed bf16x4 (8B) stores (D^T layout)
#pragma unroll
  for (int mm = 0; mm < 8; ++mm) {
    const int row = rowBase + wm * 128 + (mm >> 2) * 64 + (mm & 3) * 16 + fr;
#pragma unroll
    for (int n = 0; n < 4; ++n) {
      const int col0 = colBase + wn * 64 + n * 16 + kg * 4;
      ushort4 o;
      o.x = f2bf(fmaxf(acc[mm][n][0] + bias[col0 + 0], 0.f));
      o.y = f2bf(fmaxf(acc[mm][n][1] + bias[col0 + 1], 0.f));
      o.z = f2bf(fmaxf(acc[mm][n][2] + bias[col0 + 2], 0.f));
      o.w = f2bf(fmaxf(acc[mm][n][3] + bias[col0 + 3], 0.f));
      *reinterpret_cast<ushort4*>(&C[(size_t)row * N + col0]) = o;
    }
  }
}

// ---------------- gemm3f: fused GEMM3 (128x256 tile, K=512) + W4 GEMV + softmax
__global__ __launch_bounds__(512, 2) void gemm3f(
    const u16* __restrict__ A, const u16* __restrict__ Wt,
    const float* __restrict__ bias, const float* __restrict__ W4,
    const float* __restrict__ b4, float* __restrict__ out, int gm) {
  constexpr int K = 512, NT = 16;
  __shared__ __align__(16) u16 lds[2][12288];   // per buf: A[128][32] (4096) + B[256][32] (8192)
  __shared__ float w4s[512];
  __shared__ float zred[4][128][2];
  const int tid  = threadIdx.x;
  const int w    = tid >> 6;
  const int lane = tid & 63;
  const int fr   = lane & 15;
  const int kg   = lane >> 4;
  const int wm   = w >> 2;      // 0..1
  const int wn   = w & 3;       // 0..3

  const int nwg = gridDim.x;
  const int q = nwg >> 3, r = nwg & 7;
  const int xcd = blockIdx.x & 7, lid = blockIdx.x >> 3;
  const int swz = (xcd < r) ? (xcd * (q + 1) + lid) : (r * (q + 1) + (xcd - r) * q + lid);
  const int rowBase = swz * 128;

  if (tid < 512) w4s[tid] = W4[tid];

  const int xslot = (tid & 3) ^ ((tid >> 3) & 3);
  const u16* Asrc  = A  + (size_t)(rowBase + (tid >> 2)) * K + xslot * 8;
  const u16* Bsrc0 = Wt + (size_t)(tid >> 2) * K + xslot * 8;           // cols 0..127
  const u16* Bsrc1 = Wt + (size_t)((tid >> 2) + 128) * K + xslot * 8;   // cols 128..255

  auto stage = [&](int buf, int kt) {
    const int ko = kt * 32;
    gload16(Asrc  + ko, &lds[buf][tid * 8]);
    gload16(Bsrc0 + ko, &lds[buf][4096 + tid * 8]);
    gload16(Bsrc1 + ko, &lds[buf][8192 + tid * 8]);
  };

  f32x4 acc[4][4];
#pragma unroll
  for (int m = 0; m < 4; ++m)
#pragma unroll
    for (int n = 0; n < 4; ++n)
      acc[m][n] = f32x4{0.f, 0.f, 0.f, 0.f};

  const int aslot8 = (kg ^ ((fr >> 1) & 3)) * 8;
  const int ardA = (wm * 64 + fr) * 32 + aslot8;           // + m*512
  const int ardB = 4096 + (wn * 64 + fr) * 32 + aslot8;    // + n*512

  stage(0, 0);
  stage(1, 1);

  for (int t = 0; t < NT; ++t) {
    const int cb = t & 1;
    if (t < NT - 1) asm volatile("s_waitcnt vmcnt(3)" ::: "memory");
    else            asm volatile("s_waitcnt vmcnt(0)" ::: "memory");
    __builtin_amdgcn_s_barrier();

    bf16x8 a0 = *(const bf16x8*)&lds[cb][ardA + 0 * 512];
    bf16x8 a1 = *(const bf16x8*)&lds[cb][ardA + 1 * 512];
    bf16x8 a2 = *(const bf16x8*)&lds[cb][ardA + 2 * 512];
    bf16x8 a3 = *(const bf16x8*)&lds[cb][ardA + 3 * 512];
    bf16x8 b0 = *(const bf16x8*)&lds[cb][ardB + 0 * 512];
    bf16x8 b1 = *(const bf16x8*)&lds[cb][ardB + 1 * 512];
    bf16x8 b2 = *(const bf16x8*)&lds[cb][ardB + 2 * 512];
    bf16x8 b3 = *(const bf16x8*)&lds[cb][ardB + 3 * 512];
    asm volatile("s_waitcnt lgkmcnt(0)" ::: "memory");
    __builtin_amdgcn_s_barrier();     // all waves' reads of buf cb drained
    if (t + 2 < NT) stage(cb, t + 2); // overwrite cb safely; consumers hold regs
    __builtin_amdgcn_sched_barrier(0);
    __builtin_amdgcn_s_setprio(1);
#pragma unroll
    for (int n = 0; n < 4; ++n) {
      bf16x8 bf = (n == 0) ? b0 : (n == 1) ? b1 : (n == 2) ? b2 : b3;
      acc[0][n] = __builtin_amdgcn_mfma_f32_16x16x32_bf16(bf, a0, acc[0][n], 0, 0, 0);
      acc[1][n] = __builtin_amdgcn_mfma_f32_16x16x32_bf16(bf, a1, acc[1][n], 0, 0, 0);
      acc[2][n] = __builtin_amdgcn_mfma_f32_16x16x32_bf16(bf, a2, acc[2][n], 0, 0, 0);
      acc[3][n] = __builtin_amdgcn_mfma_f32_16x16x32_bf16(bf, a3, acc[3][n], 0, 0, 0);
    }
    __builtin_amdgcn_s_setprio(0);
  }

  float z0[4] = {0.f, 0.f, 0.f, 0.f};
  float z1[4] = {0.f, 0.f, 0.f, 0.f};
#pragma unroll
  for (int n = 0; n < 4; ++n) {
    const int col0 = wn * 64 + n * 16 + kg * 4;
#pragma unroll
    for (int j = 0; j < 4; ++j) {
      const int c = col0 + j;
      const float bv = bias[c];
      const float w40 = w4s[c * 2];
      const float w41 = w4s[c * 2 + 1];
#pragma unroll
      for (int m = 0; m < 4; ++m) {
        const float h = fmaxf(acc[m][n][j] + bv, 0.f);
        z0[m] += h * w40;
        z1[m] += h * w41;
      }
    }
  }
#pragma unroll
  for (int m = 0; m < 4; ++m) {
    z0[m] += __shfl_xor(z0[m], 16); z0[m] += __shfl_xor(z0[m], 32);
    z1[m] += __shfl_xor(z1[m], 16); z1[m] += __shfl_xor(z1[m], 32);
  }
  if (kg == 0) {
#pragma unroll
    for (int m = 0; m < 4; ++m) {
      const int rr = wm * 64 + m * 16 + fr;
      zred[wn][rr][0] = z0[m];
      zred[wn][rr][1] = z1[m];
    }
  }
  __syncthreads();
  if (tid < 128) {
    const float s0 = zred[0][tid][0] + zred[1][tid][0] + zred[2][tid][0] + zred[3][tid][0];
    const float s1 = zred[0][tid][1] + zred[1][tid][1] + zred[2][tid][1] + zred[3][tid][1];
    const float zz0 = fmaxf(s0 + b4[0], 0.f);
    const float zz1 = fmaxf(s1 + b4[1], 0.f);
    const float mx = fmaxf(zz0, zz1);
    const float e0 = __expf(zz0 - mx), e1 = __expf(zz1 - mx);
    const float inv = 1.0f / (e0 + e1);
    out[(size_t)(rowBase + tid) * 2]     = e0 * inv;
    out[(size_t)(rowBase + tid) * 2 + 1] = e1 * inv;
  }
}

// ---------------- host side
extern "C" void kernel_launch(void* const* d_in, const int* in_sizes, int n_in,
                              void* d_out, int out_size, void* d_ws, size_t ws_size,
                              hipStream_t stream) {
  const float* W1 = (const float*)d_in[32];
  const float* b1 = (const float*)d_in[33];
  const float* W2 = (const float*)d_in[34];
  const float* b2 = (const float*)d_in[35];
  const float* W3 = (const float*)d_in[36];
  const float* b3 = (const float*)d_in[37];
  const float* W4 = (const float*)d_in[38];
  const float* b4 = (const float*)d_in[39];

  (void)hipFuncSetAttribute(reinterpret_cast<const void*>(&gemm8),
                            hipFuncAttributeMaxDynamicSharedMemorySize, 65536);

  char* ws = (char*)d_ws;
  size_t off = 0;
  auto alloc = [&](size_t bytes) -> void* {
    void* p = ws + off;
    off += (bytes + 255) & ~(size_t)255;
    return p;
  };

  u16* W1t = (u16*)alloc((size_t)1024 * KPAD1 * 2);
  u16* W2t = (u16*)alloc((size_t)512 * 1024 * 2);
  u16* W3t = (u16*)alloc((size_t)256 * 512 * 2);
  const size_t fixed = off;

  // per-chunk: X (Bc x 1440) + H1 (Bc x 1024); H2 aliases X (dead after GEMM1)
  int nc = 64;
  const int cands[7] = {1, 2, 4, 8, 16, 32, 64};
  for (int ci = 0; ci < 7; ++ci) {
    size_t Bc = (size_t)B_TOTAL / cands[ci];
    size_t need = fixed + Bc * (KPAD1 + 1024) * 2 + 4096;
    if (need <= ws_size) { nc = cands[ci]; break; }
  }
  const int Bc = B_TOTAL / nc;

  u16* X  = (u16*)alloc((size_t)Bc * KPAD1 * 2);
  u16* H1 = (u16*)alloc((size_t)Bc * 1024 * 2);
  u16* H2 = X;   // Bc x 512, aliases X (X dead after GEMM1)

  wprep_kernel<<<(1024 * KPAD1 + 255) / 256, 256, 0, stream>>>(W1, W1t, 1424, 1024, KPAD1);
  wprep_kernel<<<(512 * 1024 + 255) / 256, 256, 0, stream>>>(W2, W2t, 1024, 512, 1024);
  wprep_kernel<<<(256 * 512 + 255) / 256, 256, 0, stream>>>(W3, W3t, 512, 256, 512);

  GatherArgs ga;
  for (int f = 0; f < 15; ++f) {
    ga.idx[f] = (const int*)d_in[2 * f];
    ga.E[f]   = (const float*)d_in[2 * f + 1];
  }
  ga.idx_u = (const int*)d_in[30];
  ga.E_u   = (const float*)d_in[31];

  const int gm = Bc / 256;
  for (int c = 0; c < nc; ++c) {
    gather_kernel<<<Bc / 4, 256, 0, stream>>>(ga, X, c * Bc);
    gemm8<<<gm * (1024 / 256), 512, 65536, stream>>>(X, W1t, b1, H1, Bc, 1024, KPAD1, gm);
    gemm8<<<gm * (512 / 256), 512, 65536, stream>>>(H1, W2t, b2, H2, Bc, 512, 1024, gm);
    gemm3f<<<Bc / 128, 512, 0, stream>>>(H2, W3t, b3, W4, b4,
                                         (float*)d_out + (size_t)c * Bc * 2, Bc / 128);
  }
}

// Round 15
// 446.157 us; speedup vs baseline: 1.2558x; 1.0313x over previous
//
#include <hip/hip_runtime.h>
#include <stdint.h>

typedef unsigned short u16;
typedef __attribute__((ext_vector_type(8))) __bf16 bf16x8;
typedef __attribute__((ext_vector_type(4))) float f32x4;

#define B_TOTAL 65536
#define KPAD1   1440   // 1424 padded to multiple of 32

__device__ __forceinline__ u16 f2bf(float f) {
  union { float f; uint32_t u; } v; v.f = f;
  uint32_t r = v.u + 0x7fffu + ((v.u >> 16) & 1u);
  return (u16)(r >> 16);
}
__device__ __forceinline__ float bf2f(u16 h) {
  union { uint32_t u; float f; } v; v.u = ((uint32_t)h) << 16;
  return v.f;
}

__device__ __forceinline__ void gload16(const void* g, void* lds) {
  __builtin_amdgcn_global_load_lds(
      (const __attribute__((address_space(1))) uint32_t*)g,
      (__attribute__((address_space(3))) uint32_t*)lds, 16, 0, 0);
}

// ---------------- weight prep: f32 [K][N] -> bf16 [N][Kpad] (transposed, zero-padded K)
__global__ void wprep_kernel(const float* __restrict__ W, u16* __restrict__ Wt,
                             int K, int N, int Kpad) {
  int o = blockIdx.x * 256 + threadIdx.x;
  if (o >= N * Kpad) return;
  int k = o % Kpad;
  int n = o / Kpad;
  float v = (k < K) ? W[(size_t)k * N + n] : 0.0f;
  Wt[o] = f2bf(v);
}

// ---------------- gather + concat -> X bf16 [Bc][1440]
struct GatherArgs {
  const int*   idx[15];
  const float* E[15];
  const int*   idx_u;
  const float* E_u;
};

constexpr int FDIM[15] = {128,128,128,16,16,96,144,64,80,64,48,144,96,16,144};
constexpr int FOFF[15] = {0,128,256,384,400,416,512,656,720,800,864,912,1056,1152,1168};

// 512 threads = 8 rows/block; E_userids table (69x112 f32 = 30.9KB) lives in LDS
__global__ __launch_bounds__(512) void gather_kernel(GatherArgs p, u16* __restrict__ X,
                                                     int row_base) {
  __shared__ float eu_t[69 * 112];   // 30912 B
  const int tid = threadIdx.x;

  // coalesced table preload: 69*28 = 1932 float4s over 512 threads
  {
    const float4* s4 = reinterpret_cast<const float4*>(p.E_u);
    float4* d4 = reinterpret_cast<float4*>(eu_t);
    for (int i = tid; i < 69 * 28; i += 512) d4[i] = s4[i];
  }

  const int lane = tid & 63;
  const int row  = blockIdx.x * 8 + (tid >> 6);
  const int grow = row_base + row;
  u16* xrow = X + (size_t)row * KPAD1;

  // preload userids indices: lane j (<50) holds iu[j]; ids broadcast via shfl
  const int* iu = p.idx_u + (size_t)grow * 50;
  const int myid = (lane < 50) ? iu[lane] : 0;

#pragma unroll
  for (int f = 0; f < 15; ++f) {
    const int id = p.idx[f][grow];
    const float* src = p.E[f] + (size_t)id * FDIM[f];
    const int ng = FDIM[f] / 4;
    if (lane < ng) {
      const float4 v = *reinterpret_cast<const float4*>(src + lane * 4);
      ushort4 o;
      o.x = f2bf(v.x); o.y = f2bf(v.y); o.z = f2bf(v.z); o.w = f2bf(v.w);
      *reinterpret_cast<ushort4*>(xrow + FOFF[f] + lane * 4) = o;
    }
  }

  __syncthreads();   // table ready

  // userids mean-pool over 50, dim 112: halves split j-range; reads hit LDS
  const int half = lane >> 5;
  const int c    = lane & 31;
  float4 s = {0.f, 0.f, 0.f, 0.f};
  if (c < 28) {
    const float* eu = eu_t + c * 4;
    const int j0 = half * 25;
#pragma unroll
    for (int jb = 0; jb < 25; jb += 5) {
      float4 v0, v1, v2, v3, v4;
      {
        const int i0 = __shfl(myid, j0 + jb + 0);
        const int i1 = __shfl(myid, j0 + jb + 1);
        const int i2 = __shfl(myid, j0 + jb + 2);
        const int i3 = __shfl(myid, j0 + jb + 3);
        const int i4 = __shfl(myid, j0 + jb + 4);
        v0 = *reinterpret_cast<const float4*>(eu + i0 * 112);
        v1 = *reinterpret_cast<const float4*>(eu + i1 * 112);
        v2 = *reinterpret_cast<const float4*>(eu + i2 * 112);
        v3 = *reinterpret_cast<const float4*>(eu + i3 * 112);
        v4 = *reinterpret_cast<const float4*>(eu + i4 * 112);
      }
      s.x += v0.x + v1.x + v2.x + v3.x + v4.x;
      s.y += v0.y + v1.y + v2.y + v3.y + v4.y;
      s.z += v0.z + v1.z + v2.z + v3.z + v4.z;
      s.w += v0.w + v1.w + v2.w + v3.w + v4.w;
    }
    s.x += __shfl_xor(s.x, 32);
    s.y += __shfl_xor(s.y, 32);
    s.z += __shfl_xor(s.z, 32);
    s.w += __shfl_xor(s.w, 32);
    if (half == 0) {
      const float inv = 1.0f / 50.0f;
      ushort4 o;
      o.x = f2bf(s.x * inv);
      o.y = f2bf(s.y * inv);
      o.z = f2bf(s.z * inv);
      o.w = f2bf(s.w * inv);
      *reinterpret_cast<ushort4*>(xrow + 1312 + c * 4) = o;
    }
  } else if (half == 1) {
    ushort4 z; z.x = 0; z.y = 0; z.z = 0; z.w = 0;
    *reinterpret_cast<ushort4*>(xrow + 1424 + (c - 28) * 4) = z;
  }
}

// ---------------- gemm8: 256x256 tile, BK=32, 3-buffer counted-vmcnt pipeline
// (R8 schedule — best measured) + bn-FAST XCD swizzle (R14 fetch cut: 194->70MB).
// Ledger: 8 loads in flight steady-state; vmcnt(4) per tile retires exactly the
// tile about to be consumed; vmcnt(0) only on the last tile. 3-buffer rotation
// is barrier-ordered (writes to (t+2)%3 only after the barrier that followed
// all reads of that buffer in tile t-1).
#define TILE_ELE 16384   // u16 elems per buffer (A 8192 + B 8192)

__global__ __launch_bounds__(512, 2) void gemm8(
    const u16* __restrict__ A, const u16* __restrict__ Wt,
    const float* __restrict__ bias, u16* __restrict__ C,
    int M, int N, int K, int gm) {
  extern __shared__ __align__(16) u16 lds[];
  const int tid  = threadIdx.x;
  const int w    = tid >> 6;
  const int lane = tid & 63;
  const int fr   = lane & 15;
  const int kg   = lane >> 4;
  const int wm   = w >> 2;      // 0..1
  const int wn   = w & 3;       // 0..3

  // bijective XCD swizzle; bn-FAST so consecutive same-XCD blocks share A panel
  const int nwg = gridDim.x;
  const int q = nwg >> 3, r = nwg & 7;
  const int xcd = blockIdx.x & 7, lid = blockIdx.x >> 3;
  const int swz = (xcd < r) ? (xcd * (q + 1) + lid) : (r * (q + 1) + (xcd - r) * q + lid);
  const int gn = N >> 8;
  const int bn = swz % gn, bm = swz / gn;
  const int rowBase = bm * 256, colBase = bn * 256;

  const int srow  = lane >> 2;
  const int sslot = (lane & 3) ^ ((lane >> 3) & 3);
  const u16* Asrc0 = A  + (size_t)(rowBase + w * 16 + srow) * K + sslot * 8;
  const u16* Bsrc0 = Wt + (size_t)(colBase + w * 16 + srow) * K + sslot * 8;
  const size_t rstep = (size_t)128 * K;

  const int NT = K / 32;

  f32x4 acc[8][4];
#pragma unroll
  for (int m = 0; m < 8; ++m)
#pragma unroll
    for (int n = 0; n < 4; ++n)
      acc[m][n] = f32x4{0.f, 0.f, 0.f, 0.f};

  const int aslot8 = (kg ^ ((fr >> 1) & 3)) * 8;
  const int ardA = (wm * 128 + fr) * 32 + aslot8;
  const int ardB = (wn * 64 + fr) * 32 + aslot8 + 8192;

  auto stage = [&](const u16* src0, int ldsElemBase, int kt) {
    const u16* s = src0 + (size_t)kt * 32;
    gload16(s,         &lds[ldsElemBase + w * 512]);
    gload16(s + rstep, &lds[ldsElemBase + w * 512 + 4096]);
  };

  stage(Asrc0, 0 * TILE_ELE,        0);
  stage(Bsrc0, 0 * TILE_ELE + 8192, 0);
  stage(Asrc0, 1 * TILE_ELE,        1);
  stage(Bsrc0, 1 * TILE_ELE + 8192, 1);

  for (int t = 0; t < NT; ++t) {
    const int cb = t % 3;
    const int sb = (t + 2) % 3;
    const bool dost = (t + 2) < NT;
    const int cA = cb * TILE_ELE;

    __builtin_amdgcn_sched_barrier(0);
    if (t < NT - 1) asm volatile("s_waitcnt vmcnt(4)" ::: "memory");
    else            asm volatile("s_waitcnt vmcnt(0)" ::: "memory");
    __builtin_amdgcn_s_barrier();
    __builtin_amdgcn_sched_barrier(0);

    bf16x8 a0 = *(const bf16x8*)&lds[cA + ardA + 0 * 512];
    bf16x8 a1 = *(const bf16x8*)&lds[cA + ardA + 1 * 512];
    bf16x8 a2 = *(const bf16x8*)&lds[cA + ardA + 2 * 512];
    bf16x8 a3 = *(const bf16x8*)&lds[cA + ardA + 3 * 512];
    bf16x8 b0 = *(const bf16x8*)&lds[cA + ardB + 0 * 512];
    bf16x8 b1 = *(const bf16x8*)&lds[cA + ardB + 1 * 512];
    bf16x8 b2 = *(const bf16x8*)&lds[cA + ardB + 2 * 512];
    bf16x8 b3 = *(const bf16x8*)&lds[cA + ardB + 3 * 512];
    bf16x8 c0 = *(const bf16x8*)&lds[cA + ardA + 2048 + 0 * 512];
    bf16x8 c1 = *(const bf16x8*)&lds[cA + ardA + 2048 + 1 * 512];
    bf16x8 c2 = *(const bf16x8*)&lds[cA + ardA + 2048 + 2 * 512];
    bf16x8 c3 = *(const bf16x8*)&lds[cA + ardA + 2048 + 3 * 512];
    if (dost) {
      stage(Asrc0, sb * TILE_ELE,        t + 2);
      stage(Bsrc0, sb * TILE_ELE + 8192, t + 2);
    }
#pragma unroll
    for (int n = 0; n < 4; ++n) {
      bf16x8 bf = (n == 0) ? b0 : (n == 1) ? b1 : (n == 2) ? b2 : b3;
      acc[0][n] = __builtin_amdgcn_mfma_f32_16x16x32_bf16(bf, a0, acc[0][n], 0, 0, 0);
      acc[1][n] = __builtin_amdgcn_mfma_f32_16x16x32_bf16(bf, a1, acc[1][n], 0, 0, 0);
      acc[2][n] = __builtin_amdgcn_mfma_f32_16x16x32_bf16(bf, a2, acc[2][n], 0, 0, 0);
      acc[3][n] = __builtin_amdgcn_mfma_f32_16x16x32_bf16(bf, a3, acc[3][n], 0, 0, 0);
      acc[4][n] = __builtin_amdgcn_mfma_f32_16x16x32_bf16(bf, c0, acc[4][n], 0, 0, 0);
      acc[5][n] = __builtin_amdgcn_mfma_f32_16x16x32_bf16(bf, c1, acc[5][n], 0, 0, 0);
      acc[6][n] = __builtin_amdgcn_mfma_f32_16x16x32_bf16(bf, c2, acc[6][n], 0, 0, 0);
      acc[7][n] = __builtin_amdgcn_mfma_f32_16x16x32_bf16(bf, c3, acc[7][n], 0, 0, 0);
    }
  }

  // epilogue: bias + relu + packed bf16x4 (8B) stores (D^T layout)
#pragma unroll
  for (int mm = 0; mm < 8; ++mm) {
    const int row = rowBase + wm * 128 + (mm >> 2) * 64 + (mm & 3) * 16 + fr;
#pragma unroll
    for (int n = 0; n < 4; ++n) {
      const int col0 = colBase + wn * 64 + n * 16 + kg * 4;
      ushort4 o;
      o.x = f2bf(fmaxf(acc[mm][n][0] + bias[col0 + 0], 0.f));
      o.y = f2bf(fmaxf(acc[mm][n][1] + bias[col0 + 1], 0.f));
      o.z = f2bf(fmaxf(acc[mm][n][2] + bias[col0 + 2], 0.f));
      o.w = f2bf(fmaxf(acc[mm][n][3] + bias[col0 + 3], 0.f));
      *reinterpret_cast<ushort4*>(&C[(size_t)row * N + col0]) = o;
    }
  }
}

// ---------------- gemm3f: fused GEMM3 (128x256 tile, K=512) + W4 GEMV + softmax
__global__ __launch_bounds__(512, 2) void gemm3f(
    const u16* __restrict__ A, const u16* __restrict__ Wt,
    const float* __restrict__ bias, const float* __restrict__ W4,
    const float* __restrict__ b4, float* __restrict__ out, int gm) {
  constexpr int K = 512, NT = 16;
  __shared__ __align__(16) u16 lds[2][12288];   // per buf: A[128][32] (4096) + B[256][32] (8192)
  __shared__ float w4s[512];
  __shared__ float zred[4][128][2];
  const int tid  = threadIdx.x;
  const int w    = tid >> 6;
  const int lane = tid & 63;
  const int fr   = lane & 15;
  const int kg   = lane >> 4;
  const int wm   = w >> 2;      // 0..1
  const int wn   = w & 3;       // 0..3

  const int nwg = gridDim.x;
  const int q = nwg >> 3, r = nwg & 7;
  const int xcd = blockIdx.x & 7, lid = blockIdx.x >> 3;
  const int swz = (xcd < r) ? (xcd * (q + 1) + lid) : (r * (q + 1) + (xcd - r) * q + lid);
  const int rowBase = swz * 128;

  if (tid < 512) w4s[tid] = W4[tid];

  const int xslot = (tid & 3) ^ ((tid >> 3) & 3);
  const u16* Asrc  = A  + (size_t)(rowBase + (tid >> 2)) * K + xslot * 8;
  const u16* Bsrc0 = Wt + (size_t)(tid >> 2) * K + xslot * 8;           // cols 0..127
  const u16* Bsrc1 = Wt + (size_t)((tid >> 2) + 128) * K + xslot * 8;   // cols 128..255

  auto stage = [&](int buf, int kt) {
    const int ko = kt * 32;
    gload16(Asrc  + ko, &lds[buf][tid * 8]);
    gload16(Bsrc0 + ko, &lds[buf][4096 + tid * 8]);
    gload16(Bsrc1 + ko, &lds[buf][8192 + tid * 8]);
  };

  f32x4 acc[4][4];
#pragma unroll
  for (int m = 0; m < 4; ++m)
#pragma unroll
    for (int n = 0; n < 4; ++n)
      acc[m][n] = f32x4{0.f, 0.f, 0.f, 0.f};

  const int aslot8 = (kg ^ ((fr >> 1) & 3)) * 8;
  const int ardA = (wm * 64 + fr) * 32 + aslot8;           // + m*512
  const int ardB = 4096 + (wn * 64 + fr) * 32 + aslot8;    // + n*512

  stage(0, 0);
  stage(1, 1);

  for (int t = 0; t < NT; ++t) {
    const int cb = t & 1;
    if (t < NT - 1) asm volatile("s_waitcnt vmcnt(3)" ::: "memory");
    else            asm volatile("s_waitcnt vmcnt(0)" ::: "memory");
    __builtin_amdgcn_s_barrier();

    bf16x8 a0 = *(const bf16x8*)&lds[cb][ardA + 0 * 512];
    bf16x8 a1 = *(const bf16x8*)&lds[cb][ardA + 1 * 512];
    bf16x8 a2 = *(const bf16x8*)&lds[cb][ardA + 2 * 512];
    bf16x8 a3 = *(const bf16x8*)&lds[cb][ardA + 3 * 512];
    bf16x8 b0 = *(const bf16x8*)&lds[cb][ardB + 0 * 512];
    bf16x8 b1 = *(const bf16x8*)&lds[cb][ardB + 1 * 512];
    bf16x8 b2 = *(const bf16x8*)&lds[cb][ardB + 2 * 512];
    bf16x8 b3 = *(const bf16x8*)&lds[cb][ardB + 3 * 512];
    asm volatile("s_waitcnt lgkmcnt(0)" ::: "memory");
    __builtin_amdgcn_s_barrier();     // all waves' reads of buf cb drained
    if (t + 2 < NT) stage(cb, t + 2); // overwrite cb safely; consumers hold regs
    __builtin_amdgcn_sched_barrier(0);
    __builtin_amdgcn_s_setprio(1);
#pragma unroll
    for (int n = 0; n < 4; ++n) {
      bf16x8 bf = (n == 0) ? b0 : (n == 1) ? b1 : (n == 2) ? b2 : b3;
      acc[0][n] = __builtin_amdgcn_mfma_f32_16x16x32_bf16(bf, a0, acc[0][n], 0, 0, 0);
      acc[1][n] = __builtin_amdgcn_mfma_f32_16x16x32_bf16(bf, a1, acc[1][n], 0, 0, 0);
      acc[2][n] = __builtin_amdgcn_mfma_f32_16x16x32_bf16(bf, a2, acc[2][n], 0, 0, 0);
      acc[3][n] = __builtin_amdgcn_mfma_f32_16x16x32_bf16(bf, a3, acc[3][n], 0, 0, 0);
    }
    __builtin_amdgcn_s_setprio(0);
  }

  float z0[4] = {0.f, 0.f, 0.f, 0.f};
  float z1[4] = {0.f, 0.f, 0.f, 0.f};
#pragma unroll
  for (int n = 0; n < 4; ++n) {
    const int col0 = wn * 64 + n * 16 + kg * 4;
#pragma unroll
    for (int j = 0; j < 4; ++j) {
      const int c = col0 + j;
      const float bv = bias[c];
      const float w40 = w4s[c * 2];
      const float w41 = w4s[c * 2 + 1];
#pragma unroll
      for (int m = 0; m < 4; ++m) {
        const float h = fmaxf(acc[m][n][j] + bv, 0.f);
        z0[m] += h * w40;
        z1[m] += h * w41;
      }
    }
  }
#pragma unroll
  for (int m = 0; m < 4; ++m) {
    z0[m] += __shfl_xor(z0[m], 16); z0[m] += __shfl_xor(z0[m], 32);
    z1[m] += __shfl_xor(z1[m], 16); z1[m] += __shfl_xor(z1[m], 32);
  }
  if (kg == 0) {
#pragma unroll
    for (int m = 0; m < 4; ++m) {
      const int rr = wm * 64 + m * 16 + fr;
      zred[wn][rr][0] = z0[m];
      zred[wn][rr][1] = z1[m];
    }
  }
  __syncthreads();
  if (tid < 128) {
    const float s0 = zred[0][tid][0] + zred[1][tid][0] + zred[2][tid][0] + zred[3][tid][0];
    const float s1 = zred[0][tid][1] + zred[1][tid][1] + zred[2][tid][1] + zred[3][tid][1];
    const float zz0 = fmaxf(s0 + b4[0], 0.f);
    const float zz1 = fmaxf(s1 + b4[1], 0.f);
    const float mx = fmaxf(zz0, zz1);
    const float e0 = __expf(zz0 - mx), e1 = __expf(zz1 - mx);
    const float inv = 1.0f / (e0 + e1);
    out[(size_t)(rowBase + tid) * 2]     = e0 * inv;
    out[(size_t)(rowBase + tid) * 2 + 1] = e1 * inv;
  }
}

// ---------------- host side
extern "C" void kernel_launch(void* const* d_in, const int* in_sizes, int n_in,
                              void* d_out, int out_size, void* d_ws, size_t ws_size,
                              hipStream_t stream) {
  const float* W1 = (const float*)d_in[32];
  const float* b1 = (const float*)d_in[33];
  const float* W2 = (const float*)d_in[34];
  const float* b2 = (const float*)d_in[35];
  const float* W3 = (const float*)d_in[36];
  const float* b3 = (const float*)d_in[37];
  const float* W4 = (const float*)d_in[38];
  const float* b4 = (const float*)d_in[39];

  (void)hipFuncSetAttribute(reinterpret_cast<const void*>(&gemm8),
                            hipFuncAttributeMaxDynamicSharedMemorySize, 98304);

  char* ws = (char*)d_ws;
  size_t off = 0;
  auto alloc = [&](size_t bytes) -> void* {
    void* p = ws + off;
    off += (bytes + 255) & ~(size_t)255;
    return p;
  };

  u16* W1t = (u16*)alloc((size_t)1024 * KPAD1 * 2);
  u16* W2t = (u16*)alloc((size_t)512 * 1024 * 2);
  u16* W3t = (u16*)alloc((size_t)256 * 512 * 2);
  const size_t fixed = off;

  // per-chunk: X (Bc x 1440) + H1 (Bc x 1024); H2 aliases X (dead after GEMM1)
  int nc = 64;
  const int cands[7] = {1, 2, 4, 8, 16, 32, 64};
  for (int ci = 0; ci < 7; ++ci) {
    size_t Bc = (size_t)B_TOTAL / cands[ci];
    size_t need = fixed + Bc * (KPAD1 + 1024) * 2 + 4096;
    if (need <= ws_size) { nc = cands[ci]; break; }
  }
  const int Bc = B_TOTAL / nc;

  u16* X  = (u16*)alloc((size_t)Bc * KPAD1 * 2);
  u16* H1 = (u16*)alloc((size_t)Bc * 1024 * 2);
  u16* H2 = X;   // Bc x 512, aliases X (X dead after GEMM1)

  wprep_kernel<<<(1024 * KPAD1 + 255) / 256, 256, 0, stream>>>(W1, W1t, 1424, 1024, KPAD1);
  wprep_kernel<<<(512 * 1024 + 255) / 256, 256, 0, stream>>>(W2, W2t, 1024, 512, 1024);
  wprep_kernel<<<(256 * 512 + 255) / 256, 256, 0, stream>>>(W3, W3t, 512, 256, 512);

  GatherArgs ga;
  for (int f = 0; f < 15; ++f) {
    ga.idx[f] = (const int*)d_in[2 * f];
    ga.E[f]   = (const float*)d_in[2 * f + 1];
  }
  ga.idx_u = (const int*)d_in[30];
  ga.E_u   = (const float*)d_in[31];

  const int gm = Bc / 256;
  for (int c = 0; c < nc; ++c) {
    gather_kernel<<<Bc / 8, 512, 0, stream>>>(ga, X, c * Bc);
    gemm8<<<gm * (1024 / 256), 512, 98304, stream>>>(X, W1t, b1, H1, Bc, 1024, KPAD1, gm);
    gemm8<<<gm * (512 / 256), 512, 98304, stream>>>(H1, W2t, b2, H2, Bc, 512, 1024, gm);
    gemm3f<<<Bc / 128, 512, 0, stream>>>(H2, W3t, b3, W4, b4,
                                         (float*)d_out + (size_t)c * Bc * 2, Bc / 128);
  }
}

// Round 16
// 369.728 us; speedup vs baseline: 1.5153x; 1.2067x over previous
//
#include <hip/hip_runtime.h>
#include <stdint.h>

typedef unsigned short u16;
typedef __attribute__((ext_vector_type(8))) __bf16 bf16x8;
typedef __attribute__((ext_vector_type(4))) float f32x4;

#define B_TOTAL 65536
#define KPAD1   1440   // 1424 padded (pooled feature padded to 128 cols)

__device__ __forceinline__ u16 f2bf(float f) {
  union { float f; uint32_t u; } v; v.f = f;
  uint32_t r = v.u + 0x7fffu + ((v.u >> 16) & 1u);
  return (u16)(r >> 16);
}

__device__ __forceinline__ void gload16(const void* g, void* lds) {
  __builtin_amdgcn_global_load_lds(
      (const __attribute__((address_space(1))) uint32_t*)g,
      (__attribute__((address_space(3))) uint32_t*)lds, 16, 0, 0);
}

constexpr int FDIM[15] = {128,128,128,16,16,96,144,64,80,64,48,144,96,16,144};
// X column map (pooled userids = feature 15 at col 1312, dim 128 incl zero pad)
__device__ __constant__ int FOFF2[17] = {0,128,256,384,400,416,512,656,720,800,
                                         864,912,1056,1152,1168,1312,1440};
// elem offsets of each bf16 table inside ebf
__device__ __constant__ int EOFF[15] = {0,32768,65536,98304,98336,98368,101728,
                                        155008,155584,157264,158160,158496,
                                        198096,203568,203600};
__device__ __constant__ int FDIMd[15] = {128,128,128,16,16,96,144,64,80,64,48,144,96,16,144};
#define EBF_TOTAL 246080

// ---------------- weight prep: f32 [K][N] -> bf16 [N][Kpad]
__global__ void wprep_kernel(const float* __restrict__ W, u16* __restrict__ Wt,
                             int K, int N, int Kpad) {
  int o = blockIdx.x * 256 + threadIdx.x;
  if (o >= N * Kpad) return;
  int k = o % Kpad;
  int n = o / Kpad;
  float v = (k < K) ? W[(size_t)k * N + n] : 0.0f;
  Wt[o] = f2bf(v);
}

// ---------------- embedding table convert: 15 f32 tables -> one bf16 blob
struct EcvtArgs { const float* E[15]; };
__global__ void ecvt_kernel(EcvtArgs p, u16* __restrict__ ebf) {
  int i = blockIdx.x * 256 + threadIdx.x;
  if (i >= EBF_TOTAL) return;
  int f = 0;
#pragma unroll
  for (int t = 1; t < 15; ++t) if (i >= EOFF[t]) f = t;
  ebf[i] = f2bf(p.E[f][i - EOFF[f]]);
}

// ---------------- pool: userids mean over 50 -> P[Bc][128] bf16 (cols 112..127 = 0)
__global__ __launch_bounds__(512) void pool_kernel(const int* __restrict__ idx_u,
                                                   const float* __restrict__ E_u,
                                                   u16* __restrict__ P, int row_base) {
  __shared__ float eu_t[69 * 112];
  const int tid = threadIdx.x;
  {
    const float4* s4 = reinterpret_cast<const float4*>(E_u);
    float4* d4 = reinterpret_cast<float4*>(eu_t);
    for (int i = tid; i < 69 * 28; i += 512) d4[i] = s4[i];
  }
  const int lane = tid & 63;
  const int row  = blockIdx.x * 8 + (tid >> 6);
  const int grow = row_base + row;
  u16* prow = P + (size_t)row * 128;

  const int* iu = idx_u + (size_t)grow * 50;
  const int myid = (lane < 50) ? iu[lane] : 0;
  __syncthreads();

  const int half = lane >> 5;
  const int c    = lane & 31;
  float4 s = {0.f, 0.f, 0.f, 0.f};
  if (c < 28) {
    const float* eu = eu_t + c * 4;
    const int j0 = half * 25;
#pragma unroll
    for (int jb = 0; jb < 25; jb += 5) {
      float4 v0, v1, v2, v3, v4;
      {
        const int i0 = __shfl(myid, j0 + jb + 0);
        const int i1 = __shfl(myid, j0 + jb + 1);
        const int i2 = __shfl(myid, j0 + jb + 2);
        const int i3 = __shfl(myid, j0 + jb + 3);
        const int i4 = __shfl(myid, j0 + jb + 4);
        v0 = *reinterpret_cast<const float4*>(eu + i0 * 112);
        v1 = *reinterpret_cast<const float4*>(eu + i1 * 112);
        v2 = *reinterpret_cast<const float4*>(eu + i2 * 112);
        v3 = *reinterpret_cast<const float4*>(eu + i3 * 112);
        v4 = *reinterpret_cast<const float4*>(eu + i4 * 112);
      }
      s.x += v0.x + v1.x + v2.x + v3.x + v4.x;
      s.y += v0.y + v1.y + v2.y + v3.y + v4.y;
      s.z += v0.z + v1.z + v2.z + v3.z + v4.z;
      s.w += v0.w + v1.w + v2.w + v3.w + v4.w;
    }
    s.x += __shfl_xor(s.x, 32);
    s.y += __shfl_xor(s.y, 32);
    s.z += __shfl_xor(s.z, 32);
    s.w += __shfl_xor(s.w, 32);
    if (half == 0) {
      const float inv = 1.0f / 50.0f;
      ushort4 o;
      o.x = f2bf(s.x * inv);
      o.y = f2bf(s.y * inv);
      o.z = f2bf(s.z * inv);
      o.w = f2bf(s.w * inv);
      *reinterpret_cast<ushort4*>(prow + c * 4) = o;
    }
  } else if (half == 1) {
    ushort4 z; z.x = 0; z.y = 0; z.z = 0; z.w = 0;
    *reinterpret_cast<ushort4*>(prow + 112 + (c - 28) * 4) = z;
  }
}

// ---------------- gemm1g: GEMM1 with gather-on-stage A (no X buffer)
// A-tile staged by per-group descriptor {table ptr, dim, off|fid} + idx LDS table.
// Schedule = R8/R15 3-buffer counted-vmcnt free-run; bn-fast XCD swizzle.
#define TILE_ELE 16384

struct G1Args { const int* idx[15]; };

__global__ __launch_bounds__(512, 2) void gemm1g(
    G1Args p, const u16* __restrict__ ebf, const u16* __restrict__ P,
    const u16* __restrict__ Wt, const float* __restrict__ bias,
    u16* __restrict__ C, int N, int gm) {
  constexpr int K = KPAD1;
  constexpr int NT = K / 32;   // 45
  extern __shared__ __align__(16) u16 lds[];
  uint32_t* desc32 = reinterpret_cast<uint32_t*>(&lds[49152]);   // 180 x 16B
  int* idxl = reinterpret_cast<int*>(&lds[49152 + 1440]);        // 256 x 16 ints
  const int tid  = threadIdx.x;
  const int w    = tid >> 6;
  const int lane = tid & 63;
  const int fr   = lane & 15;
  const int kg   = lane >> 4;
  const int wm   = w >> 2;
  const int wn   = w & 3;

  const int nwg = gridDim.x;
  const int q = nwg >> 3, r = nwg & 7;
  const int xcd = blockIdx.x & 7, lid = blockIdx.x >> 3;
  const int swz = (xcd < r) ? (xcd * (q + 1) + lid) : (r * (q + 1) + (xcd - r) * q + lid);
  const int gn = N >> 8;
  const int bn = swz % gn, bm = swz / gn;
  const int rowBase = bm * 256, colBase = bn * 256;

  // ---- preload descriptors + idx table
  if (tid < 180) {
    const int c0 = tid * 8;
    int f = 0;
#pragma unroll
    for (int t = 1; t < 16; ++t) if (c0 >= FOFF2[t]) f = t;
    const u16* base = (f < 15) ? (ebf + EOFF[f]) : P;
    const int dim = (f < 15) ? FDIMd[f] : 128;
    const int off = c0 - FOFF2[f];
    desc32[tid * 4 + 0] = (uint32_t)(uintptr_t)base;
    desc32[tid * 4 + 1] = (uint32_t)((uintptr_t)base >> 32);
    desc32[tid * 4 + 2] = (uint32_t)dim;
    desc32[tid * 4 + 3] = (uint32_t)(off | (f << 16));
  }
#pragma unroll
  for (int f = 0; f < 15; ++f)
    if (tid < 256) idxl[tid * 16 + f] = p.idx[f][rowBase + tid];
  if (tid < 256) idxl[tid * 16 + 15] = tid;   // pooled: P is per-chunk, row-local
  __syncthreads();

  const int srow  = lane >> 2;
  const int sslot = (lane & 3) ^ ((lane >> 3) & 3);
  const u16* Bsrc0 = Wt + (size_t)(colBase + w * 16 + srow) * K + sslot * 8;
  const size_t rstep = (size_t)128 * K;
  const int r0 = w * 16 + srow;

  f32x4 acc[8][4];
#pragma unroll
  for (int m = 0; m < 8; ++m)
#pragma unroll
    for (int n = 0; n < 4; ++n)
      acc[m][n] = f32x4{0.f, 0.f, 0.f, 0.f};

  const int aslot8 = (kg ^ ((fr >> 1) & 3)) * 8;
  const int ardA = (wm * 128 + fr) * 32 + aslot8;
  const int ardB = (wn * 64 + fr) * 32 + aslot8 + 8192;

  auto stageA = [&](int ldsElemBase, int kt) {
    const int g = kt * 4 + sslot;
    const uint32_t d0 = desc32[g * 4 + 0];
    const uint32_t d1 = desc32[g * 4 + 1];
    const uint32_t d2 = desc32[g * 4 + 2];
    const uint32_t d3 = desc32[g * 4 + 3];
    const u16* base = (const u16*)(((uint64_t)d1 << 32) | (uint64_t)d0);
    const int dim = (int)d2;
    const int off = (int)(d3 & 0xffffu);
    const int fid = (int)(d3 >> 16);
    const int i0 = idxl[r0 * 16 + fid];
    const int i1 = idxl[(r0 + 128) * 16 + fid];
    gload16(base + (size_t)i0 * dim + off, &lds[ldsElemBase + w * 512]);
    gload16(base + (size_t)i1 * dim + off, &lds[ldsElemBase + w * 512 + 4096]);
  };
  auto stageB = [&](int ldsElemBase, int kt) {
    const u16* s = Bsrc0 + (size_t)kt * 32;
    gload16(s,         &lds[ldsElemBase + w * 512]);
    gload16(s + rstep, &lds[ldsElemBase + w * 512 + 4096]);
  };

  stageA(0 * TILE_ELE,        0);
  stageB(0 * TILE_ELE + 8192, 0);
  stageA(1 * TILE_ELE,        1);
  stageB(1 * TILE_ELE + 8192, 1);

  for (int t = 0; t < NT; ++t) {
    const int cb = t % 3;
    const int sb = (t + 2) % 3;
    const bool dost = (t + 2) < NT;
    const int cA = cb * TILE_ELE;

    __builtin_amdgcn_sched_barrier(0);
    if (t < NT - 1) asm volatile("s_waitcnt vmcnt(4)" ::: "memory");
    else            asm volatile("s_waitcnt vmcnt(0)" ::: "memory");
    __builtin_amdgcn_s_barrier();
    __builtin_amdgcn_sched_barrier(0);

    // stage first: its 3 idx/desc LDS reads complete before frag reads pile up
    if (dost) {
      stageA(sb * TILE_ELE,        t + 2);
      stageB(sb * TILE_ELE + 8192, t + 2);
    }

    bf16x8 a0 = *(const bf16x8*)&lds[cA + ardA + 0 * 512];
    bf16x8 a1 = *(const bf16x8*)&lds[cA + ardA + 1 * 512];
    bf16x8 a2 = *(const bf16x8*)&lds[cA + ardA + 2 * 512];
    bf16x8 a3 = *(const bf16x8*)&lds[cA + ardA + 3 * 512];
    bf16x8 b0 = *(const bf16x8*)&lds[cA + ardB + 0 * 512];
    bf16x8 b1 = *(const bf16x8*)&lds[cA + ardB + 1 * 512];
    bf16x8 b2 = *(const bf16x8*)&lds[cA + ardB + 2 * 512];
    bf16x8 b3 = *(const bf16x8*)&lds[cA + ardB + 3 * 512];
    bf16x8 c0 = *(const bf16x8*)&lds[cA + ardA + 2048 + 0 * 512];
    bf16x8 c1 = *(const bf16x8*)&lds[cA + ardA + 2048 + 1 * 512];
    bf16x8 c2 = *(const bf16x8*)&lds[cA + ardA + 2048 + 2 * 512];
    bf16x8 c3 = *(const bf16x8*)&lds[cA + ardA + 2048 + 3 * 512];
#pragma unroll
    for (int n = 0; n < 4; ++n) {
      bf16x8 bf = (n == 0) ? b0 : (n == 1) ? b1 : (n == 2) ? b2 : b3;
      acc[0][n] = __builtin_amdgcn_mfma_f32_16x16x32_bf16(bf, a0, acc[0][n], 0, 0, 0);
      acc[1][n] = __builtin_amdgcn_mfma_f32_16x16x32_bf16(bf, a1, acc[1][n], 0, 0, 0);
      acc[2][n] = __builtin_amdgcn_mfma_f32_16x16x32_bf16(bf, a2, acc[2][n], 0, 0, 0);
      acc[3][n] = __builtin_amdgcn_mfma_f32_16x16x32_bf16(bf, a3, acc[3][n], 0, 0, 0);
      acc[4][n] = __builtin_amdgcn_mfma_f32_16x16x32_bf16(bf, c0, acc[4][n], 0, 0, 0);
      acc[5][n] = __builtin_amdgcn_mfma_f32_16x16x32_bf16(bf, c1, acc[5][n], 0, 0, 0);
      acc[6][n] = __builtin_amdgcn_mfma_f32_16x16x32_bf16(bf, c2, acc[6][n], 0, 0, 0);
      acc[7][n] = __builtin_amdgcn_mfma_f32_16x16x32_bf16(bf, c3, acc[7][n], 0, 0, 0);
    }
  }

#pragma unroll
  for (int mm = 0; mm < 8; ++mm) {
    const int row = rowBase + wm * 128 + (mm >> 2) * 64 + (mm & 3) * 16 + fr;
#pragma unroll
    for (int n = 0; n < 4; ++n) {
      const int col0 = colBase + wn * 64 + n * 16 + kg * 4;
      ushort4 o;
      o.x = f2bf(fmaxf(acc[mm][n][0] + bias[col0 + 0], 0.f));
      o.y = f2bf(fmaxf(acc[mm][n][1] + bias[col0 + 1], 0.f));
      o.z = f2bf(fmaxf(acc[mm][n][2] + bias[col0 + 2], 0.f));
      o.w = f2bf(fmaxf(acc[mm][n][3] + bias[col0 + 3], 0.f));
      *reinterpret_cast<ushort4*>(&C[(size_t)row * N + col0]) = o;
    }
  }
}

// ---------------- gemm8: R15 version (3-buffer counted vmcnt + bn-fast swizzle)
__global__ __launch_bounds__(512, 2) void gemm8(
    const u16* __restrict__ A, const u16* __restrict__ Wt,
    const float* __restrict__ bias, u16* __restrict__ C,
    int M, int N, int K, int gm) {
  extern __shared__ __align__(16) u16 lds[];
  const int tid  = threadIdx.x;
  const int w    = tid >> 6;
  const int lane = tid & 63;
  const int fr   = lane & 15;
  const int kg   = lane >> 4;
  const int wm   = w >> 2;
  const int wn   = w & 3;

  const int nwg = gridDim.x;
  const int q = nwg >> 3, r = nwg & 7;
  const int xcd = blockIdx.x & 7, lid = blockIdx.x >> 3;
  const int swz = (xcd < r) ? (xcd * (q + 1) + lid) : (r * (q + 1) + (xcd - r) * q + lid);
  const int gn = N >> 8;
  const int bn = swz % gn, bm = swz / gn;
  const int rowBase = bm * 256, colBase = bn * 256;

  const int srow  = lane >> 2;
  const int sslot = (lane & 3) ^ ((lane >> 3) & 3);
  const u16* Asrc0 = A  + (size_t)(rowBase + w * 16 + srow) * K + sslot * 8;
  const u16* Bsrc0 = Wt + (size_t)(colBase + w * 16 + srow) * K + sslot * 8;
  const size_t rstep = (size_t)128 * K;

  const int NT = K / 32;

  f32x4 acc[8][4];
#pragma unroll
  for (int m = 0; m < 8; ++m)
#pragma unroll
    for (int n = 0; n < 4; ++n)
      acc[m][n] = f32x4{0.f, 0.f, 0.f, 0.f};

  const int aslot8 = (kg ^ ((fr >> 1) & 3)) * 8;
  const int ardA = (wm * 128 + fr) * 32 + aslot8;
  const int ardB = (wn * 64 + fr) * 32 + aslot8 + 8192;

  auto stage = [&](const u16* src0, int ldsElemBase, int kt) {
    const u16* s = src0 + (size_t)kt * 32;
    gload16(s,         &lds[ldsElemBase + w * 512]);
    gload16(s + rstep, &lds[ldsElemBase + w * 512 + 4096]);
  };

  stage(Asrc0, 0 * TILE_ELE,        0);
  stage(Bsrc0, 0 * TILE_ELE + 8192, 0);
  stage(Asrc0, 1 * TILE_ELE,        1);
  stage(Bsrc0, 1 * TILE_ELE + 8192, 1);

  for (int t = 0; t < NT; ++t) {
    const int cb = t % 3;
    const int sb = (t + 2) % 3;
    const bool dost = (t + 2) < NT;
    const int cA = cb * TILE_ELE;

    __builtin_amdgcn_sched_barrier(0);
    if (t < NT - 1) asm volatile("s_waitcnt vmcnt(4)" ::: "memory");
    else            asm volatile("s_waitcnt vmcnt(0)" ::: "memory");
    __builtin_amdgcn_s_barrier();
    __builtin_amdgcn_sched_barrier(0);

    bf16x8 a0 = *(const bf16x8*)&lds[cA + ardA + 0 * 512];
    bf16x8 a1 = *(const bf16x8*)&lds[cA + ardA + 1 * 512];
    bf16x8 a2 = *(const bf16x8*)&lds[cA + ardA + 2 * 512];
    bf16x8 a3 = *(const bf16x8*)&lds[cA + ardA + 3 * 512];
    bf16x8 b0 = *(const bf16x8*)&lds[cA + ardB + 0 * 512];
    bf16x8 b1 = *(const bf16x8*)&lds[cA + ardB + 1 * 512];
    bf16x8 b2 = *(const bf16x8*)&lds[cA + ardB + 2 * 512];
    bf16x8 b3 = *(const bf16x8*)&lds[cA + ardB + 3 * 512];
    bf16x8 c0 = *(const bf16x8*)&lds[cA + ardA + 2048 + 0 * 512];
    bf16x8 c1 = *(const bf16x8*)&lds[cA + ardA + 2048 + 1 * 512];
    bf16x8 c2 = *(const bf16x8*)&lds[cA + ardA + 2048 + 2 * 512];
    bf16x8 c3 = *(const bf16x8*)&lds[cA + ardA + 2048 + 3 * 512];
    if (dost) {
      stage(Asrc0, sb * TILE_ELE,        t + 2);
      stage(Bsrc0, sb * TILE_ELE + 8192, t + 2);
    }
#pragma unroll
    for (int n = 0; n < 4; ++n) {
      bf16x8 bf = (n == 0) ? b0 : (n == 1) ? b1 : (n == 2) ? b2 : b3;
      acc[0][n] = __builtin_amdgcn_mfma_f32_16x16x32_bf16(bf, a0, acc[0][n], 0, 0, 0);
      acc[1][n] = __builtin_amdgcn_mfma_f32_16x16x32_bf16(bf, a1, acc[1][n], 0, 0, 0);
      acc[2][n] = __builtin_amdgcn_mfma_f32_16x16x32_bf16(bf, a2, acc[2][n], 0, 0, 0);
      acc[3][n] = __builtin_amdgcn_mfma_f32_16x16x32_bf16(bf, a3, acc[3][n], 0, 0, 0);
      acc[4][n] = __builtin_amdgcn_mfma_f32_16x16x32_bf16(bf, c0, acc[4][n], 0, 0, 0);
      acc[5][n] = __builtin_amdgcn_mfma_f32_16x16x32_bf16(bf, c1, acc[5][n], 0, 0, 0);
      acc[6][n] = __builtin_amdgcn_mfma_f32_16x16x32_bf16(bf, c2, acc[6][n], 0, 0, 0);
      acc[7][n] = __builtin_amdgcn_mfma_f32_16x16x32_bf16(bf, c3, acc[7][n], 0, 0, 0);
    }
  }

#pragma unroll
  for (int mm = 0; mm < 8; ++mm) {
    const int row = rowBase + wm * 128 + (mm >> 2) * 64 + (mm & 3) * 16 + fr;
#pragma unroll
    for (int n = 0; n < 4; ++n) {
      const int col0 = colBase + wn * 64 + n * 16 + kg * 4;
      ushort4 o;
      o.x = f2bf(fmaxf(acc[mm][n][0] + bias[col0 + 0], 0.f));
      o.y = f2bf(fmaxf(acc[mm][n][1] + bias[col0 + 1], 0.f));
      o.z = f2bf(fmaxf(acc[mm][n][2] + bias[col0 + 2], 0.f));
      o.w = f2bf(fmaxf(acc[mm][n][3] + bias[col0 + 3], 0.f));
      *reinterpret_cast<ushort4*>(&C[(size_t)row * N + col0]) = o;
    }
  }
}

// ---------------- gemm3f: fused GEMM3 (128x256 tile, K=512) + W4 GEMV + softmax
__global__ __launch_bounds__(512, 2) void gemm3f(
    const u16* __restrict__ A, const u16* __restrict__ Wt,
    const float* __restrict__ bias, const float* __restrict__ W4,
    const float* __restrict__ b4, float* __restrict__ out, int gm) {
  constexpr int K = 512, NT = 16;
  __shared__ __align__(16) u16 lds[2][12288];
  __shared__ float w4s[512];
  __shared__ float zred[4][128][2];
  const int tid  = threadIdx.x;
  const int w    = tid >> 6;
  const int lane = tid & 63;
  const int fr   = lane & 15;
  const int kg   = lane >> 4;
  const int wm   = w >> 2;
  const int wn   = w & 3;

  const int nwg = gridDim.x;
  const int q = nwg >> 3, r = nwg & 7;
  const int xcd = blockIdx.x & 7, lid = blockIdx.x >> 3;
  const int swz = (xcd < r) ? (xcd * (q + 1) + lid) : (r * (q + 1) + (xcd - r) * q + lid);
  const int rowBase = swz * 128;

  if (tid < 512) w4s[tid] = W4[tid];

  const int xslot = (tid & 3) ^ ((tid >> 3) & 3);
  const u16* Asrc  = A  + (size_t)(rowBase + (tid >> 2)) * K + xslot * 8;
  const u16* Bsrc0 = Wt + (size_t)(tid >> 2) * K + xslot * 8;
  const u16* Bsrc1 = Wt + (size_t)((tid >> 2) + 128) * K + xslot * 8;

  auto stage = [&](int buf, int kt) {
    const int ko = kt * 32;
    gload16(Asrc  + ko, &lds[buf][tid * 8]);
    gload16(Bsrc0 + ko, &lds[buf][4096 + tid * 8]);
    gload16(Bsrc1 + ko, &lds[buf][8192 + tid * 8]);
  };

  f32x4 acc[4][4];
#pragma unroll
  for (int m = 0; m < 4; ++m)
#pragma unroll
    for (int n = 0; n < 4; ++n)
      acc[m][n] = f32x4{0.f, 0.f, 0.f, 0.f};

  const int aslot8 = (kg ^ ((fr >> 1) & 3)) * 8;
  const int ardA = (wm * 64 + fr) * 32 + aslot8;
  const int ardB = 4096 + (wn * 64 + fr) * 32 + aslot8;

  stage(0, 0);
  stage(1, 1);

  for (int t = 0; t < NT; ++t) {
    const int cb = t & 1;
    if (t < NT - 1) asm volatile("s_waitcnt vmcnt(3)" ::: "memory");
    else            asm volatile("s_waitcnt vmcnt(0)" ::: "memory");
    __builtin_amdgcn_s_barrier();

    bf16x8 a0 = *(const bf16x8*)&lds[cb][ardA + 0 * 512];
    bf16x8 a1 = *(const bf16x8*)&lds[cb][ardA + 1 * 512];
    bf16x8 a2 = *(const bf16x8*)&lds[cb][ardA + 2 * 512];
    bf16x8 a3 = *(const bf16x8*)&lds[cb][ardA + 3 * 512];
    bf16x8 b0 = *(const bf16x8*)&lds[cb][ardB + 0 * 512];
    bf16x8 b1 = *(const bf16x8*)&lds[cb][ardB + 1 * 512];
    bf16x8 b2 = *(const bf16x8*)&lds[cb][ardB + 2 * 512];
    bf16x8 b3 = *(const bf16x8*)&lds[cb][ardB + 3 * 512];
    asm volatile("s_waitcnt lgkmcnt(0)" ::: "memory");
    __builtin_amdgcn_s_barrier();
    if (t + 2 < NT) stage(cb, t + 2);
    __builtin_amdgcn_sched_barrier(0);
    __builtin_amdgcn_s_setprio(1);
#pragma unroll
    for (int n = 0; n < 4; ++n) {
      bf16x8 bf = (n == 0) ? b0 : (n == 1) ? b1 : (n == 2) ? b2 : b3;
      acc[0][n] = __builtin_amdgcn_mfma_f32_16x16x32_bf16(bf, a0, acc[0][n], 0, 0, 0);
      acc[1][n] = __builtin_amdgcn_mfma_f32_16x16x32_bf16(bf, a1, acc[1][n], 0, 0, 0);
      acc[2][n] = __builtin_amdgcn_mfma_f32_16x16x32_bf16(bf, a2, acc[2][n], 0, 0, 0);
      acc[3][n] = __builtin_amdgcn_mfma_f32_16x16x32_bf16(bf, a3, acc[3][n], 0, 0, 0);
    }
    __builtin_amdgcn_s_setprio(0);
  }

  float z0[4] = {0.f, 0.f, 0.f, 0.f};
  float z1[4] = {0.f, 0.f, 0.f, 0.f};
#pragma unroll
  for (int n = 0; n < 4; ++n) {
    const int col0 = wn * 64 + n * 16 + kg * 4;
#pragma unroll
    for (int j = 0; j < 4; ++j) {
      const int c = col0 + j;
      const float bv = bias[c];
      const float w40 = w4s[c * 2];
      const float w41 = w4s[c * 2 + 1];
#pragma unroll
      for (int m = 0; m < 4; ++m) {
        const float h = fmaxf(acc[m][n][j] + bv, 0.f);
        z0[m] += h * w40;
        z1[m] += h * w41;
      }
    }
  }
#pragma unroll
  for (int m = 0; m < 4; ++m) {
    z0[m] += __shfl_xor(z0[m], 16); z0[m] += __shfl_xor(z0[m], 32);
    z1[m] += __shfl_xor(z1[m], 16); z1[m] += __shfl_xor(z1[m], 32);
  }
  if (kg == 0) {
#pragma unroll
    for (int m = 0; m < 4; ++m) {
      const int rr = wm * 64 + m * 16 + fr;
      zred[wn][rr][0] = z0[m];
      zred[wn][rr][1] = z1[m];
    }
  }
  __syncthreads();
  if (tid < 128) {
    const float s0 = zred[0][tid][0] + zred[1][tid][0] + zred[2][tid][0] + zred[3][tid][0];
    const float s1 = zred[0][tid][1] + zred[1][tid][1] + zred[2][tid][1] + zred[3][tid][1];
    const float zz0 = fmaxf(s0 + b4[0], 0.f);
    const float zz1 = fmaxf(s1 + b4[1], 0.f);
    const float mx = fmaxf(zz0, zz1);
    const float e0 = __expf(zz0 - mx), e1 = __expf(zz1 - mx);
    const float inv = 1.0f / (e0 + e1);
    out[(size_t)(rowBase + tid) * 2]     = e0 * inv;
    out[(size_t)(rowBase + tid) * 2 + 1] = e1 * inv;
  }
}

// ---------------- host side
extern "C" void kernel_launch(void* const* d_in, const int* in_sizes, int n_in,
                              void* d_out, int out_size, void* d_ws, size_t ws_size,
                              hipStream_t stream) {
  const float* W1 = (const float*)d_in[32];
  const float* b1 = (const float*)d_in[33];
  const float* W2 = (const float*)d_in[34];
  const float* b2 = (const float*)d_in[35];
  const float* W3 = (const float*)d_in[36];
  const float* b3 = (const float*)d_in[37];
  const float* W4 = (const float*)d_in[38];
  const float* b4 = (const float*)d_in[39];

  (void)hipFuncSetAttribute(reinterpret_cast<const void*>(&gemm8),
                            hipFuncAttributeMaxDynamicSharedMemorySize, 98304);
  (void)hipFuncSetAttribute(reinterpret_cast<const void*>(&gemm1g),
                            hipFuncAttributeMaxDynamicSharedMemorySize, 117760);

  char* ws = (char*)d_ws;
  size_t off = 0;
  auto alloc = [&](size_t bytes) -> void* {
    void* p = ws + off;
    off += (bytes + 255) & ~(size_t)255;
    return p;
  };

  u16* W1t = (u16*)alloc((size_t)1024 * KPAD1 * 2);
  u16* W2t = (u16*)alloc((size_t)512 * 1024 * 2);
  u16* W3t = (u16*)alloc((size_t)256 * 512 * 2);
  u16* ebf = (u16*)alloc((size_t)EBF_TOTAL * 2);
  const size_t fixed = off;

  // per-chunk: P (Bc x 128) + H1 (Bc x 1024) + H2 (Bc x 512), bf16
  int nc = 64;
  const int cands[7] = {1, 2, 4, 8, 16, 32, 64};
  for (int ci = 0; ci < 7; ++ci) {
    size_t Bc = (size_t)B_TOTAL / cands[ci];
    size_t need = fixed + Bc * (128 + 1024 + 512) * 2 + 4096;
    if (need <= ws_size) { nc = cands[ci]; break; }
  }
  const int Bc = B_TOTAL / nc;

  u16* P  = (u16*)alloc((size_t)Bc * 128 * 2);
  u16* H1 = (u16*)alloc((size_t)Bc * 1024 * 2);
  u16* H2 = (u16*)alloc((size_t)Bc * 512 * 2);

  wprep_kernel<<<(1024 * KPAD1 + 255) / 256, 256, 0, stream>>>(W1, W1t, 1424, 1024, KPAD1);
  wprep_kernel<<<(512 * 1024 + 255) / 256, 256, 0, stream>>>(W2, W2t, 1024, 512, 1024);
  wprep_kernel<<<(256 * 512 + 255) / 256, 256, 0, stream>>>(W3, W3t, 512, 256, 512);

  EcvtArgs ea;
  for (int f = 0; f < 15; ++f) ea.E[f] = (const float*)d_in[2 * f + 1];
  ecvt_kernel<<<(EBF_TOTAL + 255) / 256, 256, 0, stream>>>(ea, ebf);

  G1Args g1;
  for (int f = 0; f < 15; ++f) g1.idx[f] = (const int*)d_in[2 * f];
  const int* idx_u = (const int*)d_in[30];
  const float* E_u = (const float*)d_in[31];

  const int gm = Bc / 256;
  for (int c = 0; c < nc; ++c) {
    // shift idx pointers by chunk base (gemm1g uses rowBase within chunk)
    G1Args g1c = g1;
    for (int f = 0; f < 15; ++f) g1c.idx[f] = g1.idx[f] + c * Bc;
    pool_kernel<<<Bc / 8, 512, 0, stream>>>(idx_u, E_u, P, c * Bc);
    gemm1g<<<gm * (1024 / 256), 512, 117760, stream>>>(g1c, ebf, P, W1t, b1, H1, 1024, gm);
    gemm8<<<gm * (512 / 256), 512, 98304, stream>>>(H1, W2t, b2, H2, Bc, 512, 1024, gm);
    gemm3f<<<Bc / 128, 512, 0, stream>>>(H2, W3t, b3, W4, b4,
                                         (float*)d_out + (size_t)c * Bc * 2, Bc / 128);
  }
}

// Round 18
// 366.694 us; speedup vs baseline: 1.5279x; 1.0083x over previous
//
#include <hip/hip_runtime.h>
#include <stdint.h>

typedef unsigned short u16;
typedef __attribute__((ext_vector_type(8))) __bf16 bf16x8;
typedef __attribute__((ext_vector_type(4))) float f32x4;

#define B_TOTAL 65536
#define KPAD1   1440   // 1424 padded (pooled feature padded to 128 cols)

__device__ __forceinline__ u16 f2bf(float f) {
  union { float f; uint32_t u; } v; v.f = f;
  uint32_t r = v.u + 0x7fffu + ((v.u >> 16) & 1u);
  return (u16)(r >> 16);
}

__device__ __forceinline__ void gload16(const void* g, void* lds) {
  __builtin_amdgcn_global_load_lds(
      (const __attribute__((address_space(1))) uint32_t*)g,
      (__attribute__((address_space(3))) uint32_t*)lds, 16, 0, 0);
}

constexpr int FDIM[15] = {128,128,128,16,16,96,144,64,80,64,48,144,96,16,144};
// X column map (pooled userids = feature 15 at col 1312, dim 128 incl zero pad)
__device__ __constant__ int FOFF2[17] = {0,128,256,384,400,416,512,656,720,800,
                                         864,912,1056,1152,1168,1312,1440};
// elem offsets of each bf16 table inside ebf
__device__ __constant__ int EOFF[15] = {0,32768,65536,98304,98336,98368,101728,
                                        155008,155584,157264,158160,158496,
                                        198096,203568,203600};
__device__ __constant__ int FDIMd[15] = {128,128,128,16,16,96,144,64,80,64,48,144,96,16,144};
#define EBF_TOTAL 246080

// ---------------- weight prep: f32 [K][N] -> bf16 [N][Kpad]
__global__ void wprep_kernel(const float* __restrict__ W, u16* __restrict__ Wt,
                             int K, int N, int Kpad) {
  int o = blockIdx.x * 256 + threadIdx.x;
  if (o >= N * Kpad) return;
  int k = o % Kpad;
  int n = o / Kpad;
  float v = (k < K) ? W[(size_t)k * N + n] : 0.0f;
  Wt[o] = f2bf(v);
}

// ---------------- embedding table convert: 15 f32 tables -> one bf16 blob
struct EcvtArgs { const float* E[15]; };
__global__ void ecvt_kernel(EcvtArgs p, u16* __restrict__ ebf) {
  int i = blockIdx.x * 256 + threadIdx.x;
  if (i >= EBF_TOTAL) return;
  int f = 0;
#pragma unroll
  for (int t = 1; t < 15; ++t) if (i >= EOFF[t]) f = t;
  ebf[i] = f2bf(p.E[f][i - EOFF[f]]);
}

// ---------------- pool: userids mean over 50 -> P[Bc][128] bf16 (cols 112..127 = 0)
// 512 threads = 8 waves, each wave handles 2 rows (16 rows/block)
__global__ __launch_bounds__(512) void pool_kernel(const int* __restrict__ idx_u,
                                                   const float* __restrict__ E_u,
                                                   u16* __restrict__ P, int row_base) {
  __shared__ float eu_t[69 * 112];
  const int tid = threadIdx.x;
  {
    const float4* s4 = reinterpret_cast<const float4*>(E_u);
    float4* d4 = reinterpret_cast<float4*>(eu_t);
    for (int i = tid; i < 69 * 28; i += 512) d4[i] = s4[i];
  }
  const int lane = tid & 63;
  const int wv   = tid >> 6;
  const int row0 = blockIdx.x * 16 + wv * 2;

  const int* iu0 = idx_u + (size_t)(row_base + row0) * 50;
  const int myid0 = (lane < 50) ? iu0[lane] : 0;
  const int myid1 = (lane < 50) ? iu0[50 + lane] : 0;
  __syncthreads();

  const int half = lane >> 5;
  const int c    = lane & 31;

  auto POOL = [&](int myid, u16* prow) {
    float4 s = {0.f, 0.f, 0.f, 0.f};
    if (c < 28) {
      const float* eu = eu_t + c * 4;
      const int j0 = half * 25;
#pragma unroll
      for (int jb = 0; jb < 25; jb += 5) {
        float4 v0, v1, v2, v3, v4;
        {
          const int i0 = __shfl(myid, j0 + jb + 0);
          const int i1 = __shfl(myid, j0 + jb + 1);
          const int i2 = __shfl(myid, j0 + jb + 2);
          const int i3 = __shfl(myid, j0 + jb + 3);
          const int i4 = __shfl(myid, j0 + jb + 4);
          v0 = *reinterpret_cast<const float4*>(eu + i0 * 112);
          v1 = *reinterpret_cast<const float4*>(eu + i1 * 112);
          v2 = *reinterpret_cast<const float4*>(eu + i2 * 112);
          v3 = *reinterpret_cast<const float4*>(eu + i3 * 112);
          v4 = *reinterpret_cast<const float4*>(eu + i4 * 112);
        }
        s.x += v0.x + v1.x + v2.x + v3.x + v4.x;
        s.y += v0.y + v1.y + v2.y + v3.y + v4.y;
        s.z += v0.z + v1.z + v2.z + v3.z + v4.z;
        s.w += v0.w + v1.w + v2.w + v3.w + v4.w;
      }
      s.x += __shfl_xor(s.x, 32);
      s.y += __shfl_xor(s.y, 32);
      s.z += __shfl_xor(s.z, 32);
      s.w += __shfl_xor(s.w, 32);
      if (half == 0) {
        const float inv = 1.0f / 50.0f;
        ushort4 o;
        o.x = f2bf(s.x * inv);
        o.y = f2bf(s.y * inv);
        o.z = f2bf(s.z * inv);
        o.w = f2bf(s.w * inv);
        *reinterpret_cast<ushort4*>(prow + c * 4) = o;
      }
    } else if (half == 1) {
      ushort4 z; z.x = 0; z.y = 0; z.z = 0; z.w = 0;
      *reinterpret_cast<ushort4*>(prow + 112 + (c - 28) * 4) = z;
    }
  };

  POOL(myid0, P + (size_t)row0 * 128);
  POOL(myid1, P + (size_t)(row0 + 1) * 128);
}

// ---------------- gemm1g: GEMM1 with gather-on-stage A (no X buffer)
// LDS byte map: [0,98304) tile bufs | [98304,101184) desc (180x16B) |
//               [101184,118592) idxl (256x17 ints, odd stride = no bank conflict)
#define TILE_ELE 16384

struct G1Args { const int* idx[15]; };

__global__ __launch_bounds__(512, 2) void gemm1g(
    G1Args p, const u16* __restrict__ ebf, const u16* __restrict__ P,
    const u16* __restrict__ Wt, const float* __restrict__ bias,
    u16* __restrict__ C, int N, int gm) {
  constexpr int K = KPAD1;
  constexpr int NT = K / 32;   // 45
  extern __shared__ __align__(16) u16 lds[];
  uint32_t* desc32 = reinterpret_cast<uint32_t*>(&lds[49152]);   // byte 98304, 2880 B
  int* idxl = reinterpret_cast<int*>(&lds[49152 + 1440]);        // byte 101184, 17408 B
  const int tid  = threadIdx.x;
  const int w    = tid >> 6;
  const int lane = tid & 63;
  const int fr   = lane & 15;
  const int kg   = lane >> 4;
  const int wm   = w >> 2;
  const int wn   = w & 3;

  const int nwg = gridDim.x;
  const int q = nwg >> 3, r = nwg & 7;
  const int xcd = blockIdx.x & 7, lid = blockIdx.x >> 3;
  const int swz = (xcd < r) ? (xcd * (q + 1) + lid) : (r * (q + 1) + (xcd - r) * q + lid);
  const int gn = N >> 8;
  const int bn = swz % gn, bm = swz / gn;
  const int rowBase = bm * 256, colBase = bn * 256;

  // ---- preload descriptors + idx table
  if (tid < 180) {
    const int c0 = tid * 8;
    int f = 0;
#pragma unroll
    for (int t = 1; t < 16; ++t) if (c0 >= FOFF2[t]) f = t;
    const u16* base = (f < 15) ? (ebf + EOFF[f]) : P;
    const int dim = (f < 15) ? FDIMd[f] : 128;
    const int off = c0 - FOFF2[f];
    desc32[tid * 4 + 0] = (uint32_t)(uintptr_t)base;
    desc32[tid * 4 + 1] = (uint32_t)((uintptr_t)base >> 32);
    desc32[tid * 4 + 2] = (uint32_t)dim;
    desc32[tid * 4 + 3] = (uint32_t)(off | (f << 16));
  }
#pragma unroll
  for (int f = 0; f < 15; ++f)
    if (tid < 256) idxl[tid * 17 + f] = p.idx[f][rowBase + tid];
  if (tid < 256) idxl[tid * 17 + 15] = tid;   // pooled: P is chunk-local
  __syncthreads();

  const int srow  = lane >> 2;
  const int sslot = (lane & 3) ^ ((lane >> 3) & 3);
  const u16* Bsrc0 = Wt + (size_t)(colBase + w * 16 + srow) * K + sslot * 8;
  const size_t rstep = (size_t)128 * K;
  const int r0 = w * 16 + srow;

  f32x4 acc[8][4];
#pragma unroll
  for (int m = 0; m < 8; ++m)
#pragma unroll
    for (int n = 0; n < 4; ++n)
      acc[m][n] = f32x4{0.f, 0.f, 0.f, 0.f};

  const int aslot8 = (kg ^ ((fr >> 1) & 3)) * 8;
  const int ardA = (wm * 128 + fr) * 32 + aslot8;
  const int ardB = (wn * 64 + fr) * 32 + aslot8 + 8192;

  auto stageA = [&](int ldsElemBase, int kt) {
    const int g = kt * 4 + sslot;
    const uint32_t d0 = desc32[g * 4 + 0];
    const uint32_t d1 = desc32[g * 4 + 1];
    const uint32_t d2 = desc32[g * 4 + 2];
    const uint32_t d3 = desc32[g * 4 + 3];
    const u16* base = (const u16*)(((uint64_t)d1 << 32) | (uint64_t)d0);
    const int dim = (int)d2;
    const int off = (int)(d3 & 0xffffu);
    const int fid = (int)(d3 >> 16);
    const int i0 = idxl[r0 * 17 + fid];
    const int i1 = idxl[(r0 + 128) * 17 + fid];
    gload16(base + (size_t)i0 * dim + off, &lds[ldsElemBase + w * 512]);
    gload16(base + (size_t)i1 * dim + off, &lds[ldsElemBase + w * 512 + 4096]);
  };
  auto stageB = [&](int ldsElemBase, int kt) {
    const u16* s = Bsrc0 + (size_t)kt * 32;
    gload16(s,         &lds[ldsElemBase + w * 512]);
    gload16(s + rstep, &lds[ldsElemBase + w * 512 + 4096]);
  };

  stageA(0 * TILE_ELE,        0);
  stageB(0 * TILE_ELE + 8192, 0);
  stageA(1 * TILE_ELE,        1);
  stageB(1 * TILE_ELE + 8192, 1);

  for (int t = 0; t < NT; ++t) {
    const int cb = t % 3;
    const int sb = (t + 2) % 3;
    const bool dost = (t + 2) < NT;
    const int cA = cb * TILE_ELE;

    __builtin_amdgcn_sched_barrier(0);
    if (t < NT - 1) asm volatile("s_waitcnt vmcnt(4)" ::: "memory");
    else            asm volatile("s_waitcnt vmcnt(0)" ::: "memory");
    __builtin_amdgcn_s_barrier();
    __builtin_amdgcn_sched_barrier(0);

    if (dost) {
      stageA(sb * TILE_ELE,        t + 2);
      stageB(sb * TILE_ELE + 8192, t + 2);
    }

    bf16x8 a0 = *(const bf16x8*)&lds[cA + ardA + 0 * 512];
    bf16x8 a1 = *(const bf16x8*)&lds[cA + ardA + 1 * 512];
    bf16x8 a2 = *(const bf16x8*)&lds[cA + ardA + 2 * 512];
    bf16x8 a3 = *(const bf16x8*)&lds[cA + ardA + 3 * 512];
    bf16x8 b0 = *(const bf16x8*)&lds[cA + ardB + 0 * 512];
    bf16x8 b1 = *(const bf16x8*)&lds[cA + ardB + 1 * 512];
    bf16x8 b2 = *(const bf16x8*)&lds[cA + ardB + 2 * 512];
    bf16x8 b3 = *(const bf16x8*)&lds[cA + ardB + 3 * 512];
    bf16x8 c0 = *(const bf16x8*)&lds[cA + ardA + 2048 + 0 * 512];
    bf16x8 c1 = *(const bf16x8*)&lds[cA + ardA + 2048 + 1 * 512];
    bf16x8 c2 = *(const bf16x8*)&lds[cA + ardA + 2048 + 2 * 512];
    bf16x8 c3 = *(const bf16x8*)&lds[cA + ardA + 2048 + 3 * 512];
#pragma unroll
    for (int n = 0; n < 4; ++n) {
      bf16x8 bf = (n == 0) ? b0 : (n == 1) ? b1 : (n == 2) ? b2 : b3;
      acc[0][n] = __builtin_amdgcn_mfma_f32_16x16x32_bf16(bf, a0, acc[0][n], 0, 0, 0);
      acc[1][n] = __builtin_amdgcn_mfma_f32_16x16x32_bf16(bf, a1, acc[1][n], 0, 0, 0);
      acc[2][n] = __builtin_amdgcn_mfma_f32_16x16x32_bf16(bf, a2, acc[2][n], 0, 0, 0);
      acc[3][n] = __builtin_amdgcn_mfma_f32_16x16x32_bf16(bf, a3, acc[3][n], 0, 0, 0);
      acc[4][n] = __builtin_amdgcn_mfma_f32_16x16x32_bf16(bf, c0, acc[4][n], 0, 0, 0);
      acc[5][n] = __builtin_amdgcn_mfma_f32_16x16x32_bf16(bf, c1, acc[5][n], 0, 0, 0);
      acc[6][n] = __builtin_amdgcn_mfma_f32_16x16x32_bf16(bf, c2, acc[6][n], 0, 0, 0);
      acc[7][n] = __builtin_amdgcn_mfma_f32_16x16x32_bf16(bf, c3, acc[7][n], 0, 0, 0);
    }
  }

#pragma unroll
  for (int mm = 0; mm < 8; ++mm) {
    const int row = rowBase + wm * 128 + (mm >> 2) * 64 + (mm & 3) * 16 + fr;
#pragma unroll
    for (int n = 0; n < 4; ++n) {
      const int col0 = colBase + wn * 64 + n * 16 + kg * 4;
      ushort4 o;
      o.x = f2bf(fmaxf(acc[mm][n][0] + bias[col0 + 0], 0.f));
      o.y = f2bf(fmaxf(acc[mm][n][1] + bias[col0 + 1], 0.f));
      o.z = f2bf(fmaxf(acc[mm][n][2] + bias[col0 + 2], 0.f));
      o.w = f2bf(fmaxf(acc[mm][n][3] + bias[col0 + 3], 0.f));
      *reinterpret_cast<ushort4*>(&C[(size_t)row * N + col0]) = o;
    }
  }
}

// ---------------- gemm8: R15 version (3-buffer counted vmcnt + bn-fast swizzle)
__global__ __launch_bounds__(512, 2) void gemm8(
    const u16* __restrict__ A, const u16* __restrict__ Wt,
    const float* __restrict__ bias, u16* __restrict__ C,
    int M, int N, int K, int gm) {
  extern __shared__ __align__(16) u16 lds[];
  const int tid  = threadIdx.x;
  const int w    = tid >> 6;
  const int lane = tid & 63;
  const int fr   = lane & 15;
  const int kg   = lane >> 4;
  const int wm   = w >> 2;
  const int wn   = w & 3;

  const int nwg = gridDim.x;
  const int q = nwg >> 3, r = nwg & 7;
  const int xcd = blockIdx.x & 7, lid = blockIdx.x >> 3;
  const int swz = (xcd < r) ? (xcd * (q + 1) + lid) : (r * (q + 1) + (xcd - r) * q + lid);
  const int gn = N >> 8;
  const int bn = swz % gn, bm = swz / gn;
  const int rowBase = bm * 256, colBase = bn * 256;

  const int srow  = lane >> 2;
  const int sslot = (lane & 3) ^ ((lane >> 3) & 3);
  const u16* Asrc0 = A  + (size_t)(rowBase + w * 16 + srow) * K + sslot * 8;
  const u16* Bsrc0 = Wt + (size_t)(colBase + w * 16 + srow) * K + sslot * 8;
  const size_t rstep = (size_t)128 * K;

  const int NT = K / 32;

  f32x4 acc[8][4];
#pragma unroll
  for (int m = 0; m < 8; ++m)
#pragma unroll
    for (int n = 0; n < 4; ++n)
      acc[m][n] = f32x4{0.f, 0.f, 0.f, 0.f};

  const int aslot8 = (kg ^ ((fr >> 1) & 3)) * 8;
  const int ardA = (wm * 128 + fr) * 32 + aslot8;
  const int ardB = (wn * 64 + fr) * 32 + aslot8 + 8192;

  auto stage = [&](const u16* src0, int ldsElemBase, int kt) {
    const u16* s = src0 + (size_t)kt * 32;
    gload16(s,         &lds[ldsElemBase + w * 512]);
    gload16(s + rstep, &lds[ldsElemBase + w * 512 + 4096]);
  };

  stage(Asrc0, 0 * TILE_ELE,        0);
  stage(Bsrc0, 0 * TILE_ELE + 8192, 0);
  stage(Asrc0, 1 * TILE_ELE,        1);
  stage(Bsrc0, 1 * TILE_ELE + 8192, 1);

  for (int t = 0; t < NT; ++t) {
    const int cb = t % 3;
    const int sb = (t + 2) % 3;
    const bool dost = (t + 2) < NT;
    const int cA = cb * TILE_ELE;

    __builtin_amdgcn_sched_barrier(0);
    if (t < NT - 1) asm volatile("s_waitcnt vmcnt(4)" ::: "memory");
    else            asm volatile("s_waitcnt vmcnt(0)" ::: "memory");
    __builtin_amdgcn_s_barrier();
    __builtin_amdgcn_sched_barrier(0);

    bf16x8 a0 = *(const bf16x8*)&lds[cA + ardA + 0 * 512];
    bf16x8 a1 = *(const bf16x8*)&lds[cA + ardA + 1 * 512];
    bf16x8 a2 = *(const bf16x8*)&lds[cA + ardA + 2 * 512];
    bf16x8 a3 = *(const bf16x8*)&lds[cA + ardA + 3 * 512];
    bf16x8 b0 = *(const bf16x8*)&lds[cA + ardB + 0 * 512];
    bf16x8 b1 = *(const bf16x8*)&lds[cA + ardB + 1 * 512];
    bf16x8 b2 = *(const bf16x8*)&lds[cA + ardB + 2 * 512];
    bf16x8 b3 = *(const bf16x8*)&lds[cA + ardB + 3 * 512];
    bf16x8 c0 = *(const bf16x8*)&lds[cA + ardA + 2048 + 0 * 512];
    bf16x8 c1 = *(const bf16x8*)&lds[cA + ardA + 2048 + 1 * 512];
    bf16x8 c2 = *(const bf16x8*)&lds[cA + ardA + 2048 + 2 * 512];
    bf16x8 c3 = *(const bf16x8*)&lds[cA + ardA + 2048 + 3 * 512];
    if (dost) {
      stage(Asrc0, sb * TILE_ELE,        t + 2);
      stage(Bsrc0, sb * TILE_ELE + 8192, t + 2);
    }
#pragma unroll
    for (int n = 0; n < 4; ++n) {
      bf16x8 bf = (n == 0) ? b0 : (n == 1) ? b1 : (n == 2) ? b2 : b3;
      acc[0][n] = __builtin_amdgcn_mfma_f32_16x16x32_bf16(bf, a0, acc[0][n], 0, 0, 0);
      acc[1][n] = __builtin_amdgcn_mfma_f32_16x16x32_bf16(bf, a1, acc[1][n], 0, 0, 0);
      acc[2][n] = __builtin_amdgcn_mfma_f32_16x16x32_bf16(bf, a2, acc[2][n], 0, 0, 0);
      acc[3][n] = __builtin_amdgcn_mfma_f32_16x16x32_bf16(bf, a3, acc[3][n], 0, 0, 0);
      acc[4][n] = __builtin_amdgcn_mfma_f32_16x16x32_bf16(bf, c0, acc[4][n], 0, 0, 0);
      acc[5][n] = __builtin_amdgcn_mfma_f32_16x16x32_bf16(bf, c1, acc[5][n], 0, 0, 0);
      acc[6][n] = __builtin_amdgcn_mfma_f32_16x16x32_bf16(bf, c2, acc[6][n], 0, 0, 0);
      acc[7][n] = __builtin_amdgcn_mfma_f32_16x16x32_bf16(bf, c3, acc[7][n], 0, 0, 0);
    }
  }

#pragma unroll
  for (int mm = 0; mm < 8; ++mm) {
    const int row = rowBase + wm * 128 + (mm >> 2) * 64 + (mm & 3) * 16 + fr;
#pragma unroll
    for (int n = 0; n < 4; ++n) {
      const int col0 = colBase + wn * 64 + n * 16 + kg * 4;
      ushort4 o;
      o.x = f2bf(fmaxf(acc[mm][n][0] + bias[col0 + 0], 0.f));
      o.y = f2bf(fmaxf(acc[mm][n][1] + bias[col0 + 1], 0.f));
      o.z = f2bf(fmaxf(acc[mm][n][2] + bias[col0 + 2], 0.f));
      o.w = f2bf(fmaxf(acc[mm][n][3] + bias[col0 + 3], 0.f));
      *reinterpret_cast<ushort4*>(&C[(size_t)row * N + col0]) = o;
    }
  }
}

// ---------------- gemm3f: fused GEMM3 (128x256 tile, K=512) + W4 GEMV + softmax
__global__ __launch_bounds__(512, 2) void gemm3f(
    const u16* __restrict__ A, const u16* __restrict__ Wt,
    const float* __restrict__ bias, const float* __restrict__ W4,
    const float* __restrict__ b4, float* __restrict__ out, int gm) {
  constexpr int K = 512, NT = 16;
  __shared__ __align__(16) u16 lds[2][12288];
  __shared__ float w4s[512];
  __shared__ float zred[4][128][2];
  const int tid  = threadIdx.x;
  const int w    = tid >> 6;
  const int lane = tid & 63;
  const int fr   = lane & 15;
  const int kg   = lane >> 4;
  const int wm   = w >> 2;
  const int wn   = w & 3;

  const int nwg = gridDim.x;
  const int q = nwg >> 3, r = nwg & 7;
  const int xcd = blockIdx.x & 7, lid = blockIdx.x >> 3;
  const int swz = (xcd < r) ? (xcd * (q + 1) + lid) : (r * (q + 1) + (xcd - r) * q + lid);
  const int rowBase = swz * 128;

  if (tid < 512) w4s[tid] = W4[tid];

  const int xslot = (tid & 3) ^ ((tid >> 3) & 3);
  const u16* Asrc  = A  + (size_t)(rowBase + (tid >> 2)) * K + xslot * 8;
  const u16* Bsrc0 = Wt + (size_t)(tid >> 2) * K + xslot * 8;
  const u16* Bsrc1 = Wt + (size_t)((tid >> 2) + 128) * K + xslot * 8;

  auto stage = [&](int buf, int kt) {
    const int ko = kt * 32;
    gload16(Asrc  + ko, &lds[buf][tid * 8]);
    gload16(Bsrc0 + ko, &lds[buf][4096 + tid * 8]);
    gload16(Bsrc1 + ko, &lds[buf][8192 + tid * 8]);
  };

  f32x4 acc[4][4];
#pragma unroll
  for (int m = 0; m < 4; ++m)
#pragma unroll
    for (int n = 0; n < 4; ++n)
      acc[m][n] = f32x4{0.f, 0.f, 0.f, 0.f};

  const int aslot8 = (kg ^ ((fr >> 1) & 3)) * 8;
  const int ardA = (wm * 64 + fr) * 32 + aslot8;
  const int ardB = 4096 + (wn * 64 + fr) * 32 + aslot8;

  stage(0, 0);
  stage(1, 1);

  for (int t = 0; t < NT; ++t) {
    const int cb = t & 1;
    if (t < NT - 1) asm volatile("s_waitcnt vmcnt(3)" ::: "memory");
    else            asm volatile("s_waitcnt vmcnt(0)" ::: "memory");
    __builtin_amdgcn_s_barrier();

    bf16x8 a0 = *(const bf16x8*)&lds[cb][ardA + 0 * 512];
    bf16x8 a1 = *(const bf16x8*)&lds[cb][ardA + 1 * 512];
    bf16x8 a2 = *(const bf16x8*)&lds[cb][ardA + 2 * 512];
    bf16x8 a3 = *(const bf16x8*)&lds[cb][ardA + 3 * 512];
    bf16x8 b0 = *(const bf16x8*)&lds[cb][ardB + 0 * 512];
    bf16x8 b1 = *(const bf16x8*)&lds[cb][ardB + 1 * 512];
    bf16x8 b2 = *(const bf16x8*)&lds[cb][ardB + 2 * 512];
    bf16x8 b3 = *(const bf16x8*)&lds[cb][ardB + 3 * 512];
    asm volatile("s_waitcnt lgkmcnt(0)" ::: "memory");
    __builtin_amdgcn_s_barrier();
    if (t + 2 < NT) stage(cb, t + 2);
    __builtin_amdgcn_sched_barrier(0);
    __builtin_amdgcn_s_setprio(1);
#pragma unroll
    for (int n = 0; n < 4; ++n) {
      bf16x8 bf = (n == 0) ? b0 : (n == 1) ? b1 : (n == 2) ? b2 : b3;
      acc[0][n] = __builtin_amdgcn_mfma_f32_16x16x32_bf16(bf, a0, acc[0][n], 0, 0, 0);
      acc[1][n] = __builtin_amdgcn_mfma_f32_16x16x32_bf16(bf, a1, acc[1][n], 0, 0, 0);
      acc[2][n] = __builtin_amdgcn_mfma_f32_16x16x32_bf16(bf, a2, acc[2][n], 0, 0, 0);
      acc[3][n] = __builtin_amdgcn_mfma_f32_16x16x32_bf16(bf, a3, acc[3][n], 0, 0, 0);
    }
    __builtin_amdgcn_s_setprio(0);
  }

  float z0[4] = {0.f, 0.f, 0.f, 0.f};
  float z1[4] = {0.f, 0.f, 0.f, 0.f};
#pragma unroll
  for (int n = 0; n < 4; ++n) {
    const int col0 = wn * 64 + n * 16 + kg * 4;
#pragma unroll
    for (int j = 0; j < 4; ++j) {
      const int c = col0 + j;
      const float bv = bias[c];
      const float w40 = w4s[c * 2];
      const float w41 = w4s[c * 2 + 1];
#pragma unroll
      for (int m = 0; m < 4; ++m) {
        const float h = fmaxf(acc[m][n][j] + bv, 0.f);
        z0[m] += h * w40;
        z1[m] += h * w41;
      }
    }
  }
#pragma unroll
  for (int m = 0; m < 4; ++m) {
    z0[m] += __shfl_xor(z0[m], 16); z0[m] += __shfl_xor(z0[m], 32);
    z1[m] += __shfl_xor(z1[m], 16); z1[m] += __shfl_xor(z1[m], 32);
  }
  if (kg == 0) {
#pragma unroll
    for (int m = 0; m < 4; ++m) {
      const int rr = wm * 64 + m * 16 + fr;
      zred[wn][rr][0] = z0[m];
      zred[wn][rr][1] = z1[m];
    }
  }
  __syncthreads();
  if (tid < 128) {
    const float s0 = zred[0][tid][0] + zred[1][tid][0] + zred[2][tid][0] + zred[3][tid][0];
    const float s1 = zred[0][tid][1] + zred[1][tid][1] + zred[2][tid][1] + zred[3][tid][1];
    const float zz0 = fmaxf(s0 + b4[0], 0.f);
    const float zz1 = fmaxf(s1 + b4[1], 0.f);
    const float mx = fmaxf(zz0, zz1);
    const float e0 = __expf(zz0 - mx), e1 = __expf(zz1 - mx);
    const float inv = 1.0f / (e0 + e1);
    out[(size_t)(rowBase + tid) * 2]     = e0 * inv;
    out[(size_t)(rowBase + tid) * 2 + 1] = e1 * inv;
  }
}

// ---------------- host side
extern "C" void kernel_launch(void* const* d_in, const int* in_sizes, int n_in,
                              void* d_out, int out_size, void* d_ws, size_t ws_size,
                              hipStream_t stream) {
  const float* W1 = (const float*)d_in[32];
  const float* b1 = (const float*)d_in[33];
  const float* W2 = (const float*)d_in[34];
  const float* b2 = (const float*)d_in[35];
  const float* W3 = (const float*)d_in[36];
  const float* b3 = (const float*)d_in[37];
  const float* W4 = (const float*)d_in[38];
  const float* b4 = (const float*)d_in[39];

  (void)hipFuncSetAttribute(reinterpret_cast<const void*>(&gemm8),
                            hipFuncAttributeMaxDynamicSharedMemorySize, 98304);
  (void)hipFuncSetAttribute(reinterpret_cast<const void*>(&gemm1g),
                            hipFuncAttributeMaxDynamicSharedMemorySize, 118784);

  char* ws = (char*)d_ws;
  size_t off = 0;
  auto alloc = [&](size_t bytes) -> void* {
    void* p = ws + off;
    off += (bytes + 255) & ~(size_t)255;
    return p;
  };

  u16* W1t = (u16*)alloc((size_t)1024 * KPAD1 * 2);
  u16* W2t = (u16*)alloc((size_t)512 * 1024 * 2);
  u16* W3t = (u16*)alloc((size_t)256 * 512 * 2);
  u16* ebf = (u16*)alloc((size_t)EBF_TOTAL * 2);
  const size_t fixed = off;

  // per-chunk: P (Bc x 128) + H1 (Bc x 1024) + H2 (Bc x 512), bf16
  int nc = 64;
  const int cands[7] = {1, 2, 4, 8, 16, 32, 64};
  for (int ci = 0; ci < 7; ++ci) {
    size_t Bc = (size_t)B_TOTAL / cands[ci];
    size_t need = fixed + Bc * (128 + 1024 + 512) * 2 + 4096;
    if (need <= ws_size) { nc = cands[ci]; break; }
  }
  const int Bc = B_TOTAL / nc;

  u16* P  = (u16*)alloc((size_t)Bc * 128 * 2);
  u16* H1 = (u16*)alloc((size_t)Bc * 1024 * 2);
  u16* H2 = (u16*)alloc((size_t)Bc * 512 * 2);

  wprep_kernel<<<(1024 * KPAD1 + 255) / 256, 256, 0, stream>>>(W1, W1t, 1424, 1024, KPAD1);
  wprep_kernel<<<(512 * 1024 + 255) / 256, 256, 0, stream>>>(W2, W2t, 1024, 512, 1024);
  wprep_kernel<<<(256 * 512 + 255) / 256, 256, 0, stream>>>(W3, W3t, 512, 256, 512);

  EcvtArgs ea;
  for (int f = 0; f < 15; ++f) ea.E[f] = (const float*)d_in[2 * f + 1];
  ecvt_kernel<<<(EBF_TOTAL + 255) / 256, 256, 0, stream>>>(ea, ebf);

  G1Args g1;
  for (int f = 0; f < 15; ++f) g1.idx[f] = (const int*)d_in[2 * f];
  const int* idx_u = (const int*)d_in[30];
  const float* E_u = (const float*)d_in[31];

  const int gm = Bc / 256;
  for (int c = 0; c < nc; ++c) {
    G1Args g1c = g1;
    for (int f = 0; f < 15; ++f) g1c.idx[f] = g1.idx[f] + c * Bc;
    pool_kernel<<<Bc / 16, 512, 0, stream>>>(idx_u, E_u, P, c * Bc);
    gemm1g<<<gm * (1024 / 256), 512, 118784, stream>>>(g1c, ebf, P, W1t, b1, H1, 1024, gm);
    gemm8<<<gm * (512 / 256), 512, 98304, stream>>>(H1, W2t, b2, H2, Bc, 512, 1024, gm);
    gemm3f<<<Bc / 128, 512, 0, stream>>>(H2, W3t, b3, W4, b4,
                                         (float*)d_out + (size_t)c * Bc * 2, Bc / 128);
  }
}